// Round 4
// baseline (308.186 us; speedup 1.0000x reference)
//
#include <hip/hip_runtime.h>
#include <math.h>

#define TOT_S   13294
#define NBATCH  2
#define CCH     512
#define MHEAD   8
#define PITCH   40   // LDS row pitch in bf16 elems (32 + 8 pad -> 80B)

typedef short     short8  __attribute__((ext_vector_type(8)));
typedef float     f32x4   __attribute__((ext_vector_type(4)));
typedef unsigned short u16x8 __attribute__((ext_vector_type(8)));
typedef unsigned short u16x4 __attribute__((ext_vector_type(4)));

__device__ __forceinline__ unsigned short f2bf(float f) {
    union { float f; unsigned int u; } v; v.f = f;
    unsigned int r = v.u + 0x7fffu + ((v.u >> 16) & 1u);   // RNE
    return (unsigned short)(r >> 16);
}
__device__ __forceinline__ float bf2f(unsigned short h) {
    union { unsigned int u; float f; } v; v.u = ((unsigned int)h) << 16;
    return v.f;
}

// ---------------------------------------------------------------------------
__global__ void cast_f32_bf16(const float* __restrict__ src,
                              unsigned short* __restrict__ dst, int n4)
{
    const int i = blockIdx.x * blockDim.x + threadIdx.x;
    if (i < n4) {
        const float4 v = *(const float4*)(src + (size_t)i * 4);
        u16x4 o;
        o[0] = f2bf(v.x); o[1] = f2bf(v.y); o[2] = f2bf(v.z); o[3] = f2bf(v.w);
        *(u16x4*)(dst + (size_t)i * 4) = o;
    }
}

// ---------------------------------------------------------------------------
// cast_transpose v3: 128s x 64c tile, 2-pass over one 64-row LDS buffer.
//   - XCD-chunked swizzle: XCD k handles 13 consecutive s-tiles (bx%8 = XCD
//     since grid.x stride 104 % 8 == 0) -> 6.6KB contiguous per row per XCD.
//   - all 32 float2 loads issued upfront (256B/thread in flight).
//   - stores: u16x8 along c, 8 lanes = one full 128B line per s row.
// ---------------------------------------------------------------------------
#define CT_P 68

__global__ __launch_bounds__(256)
void cast_transpose(const float* __restrict__ x, const float* __restrict__ pos,
                    const unsigned char* __restrict__ mask,
                    unsigned short* __restrict__ xbt,
                    unsigned short* __restrict__ xpbt)
{
    __shared__ unsigned short lx[64 * CT_P];
    __shared__ unsigned short lp[64 * CT_P];

    const int n  = blockIdx.z;
    const int cb = blockIdx.y * 64;
    const int bx = blockIdx.x;
    const int sb = ((bx & 7) * 13 + (bx >> 3)) * 128;   // XCD-chunked swizzle
    const int tid = threadIdx.x;

    // load mapping: lanes 0..15 span s (coalesced float2), tid>>4 spans c
    const int s0 = (tid & 15) * 4;           // local s quad within 64-s half
    const int c0 = (tid >> 4) * 4;           // local c quad (0..60)

    float vx[2][4][4];   // [pass][ci][si]
    float vp[2][4][4];
    bool  mk[2][4];

    // ---- issue ALL global loads upfront (2 passes x 4 c-rows x 2 float2 x 2 arrays)
#pragma unroll
    for (int p = 0; p < 2; ++p) {
        const int sg = sb + p * 64 + s0;
#pragma unroll
        for (int si = 0; si < 4; ++si)
            mk[p][si] = (sg + si < TOT_S) ? (mask[(size_t)n * TOT_S + sg + si] != 0) : false;
        const bool full = (sg + 3) < TOT_S;
#pragma unroll
        for (int ci = 0; ci < 4; ++ci) {
            const size_t rowo = ((size_t)n * CCH + cb + c0 + ci) * TOT_S + sg;
            const float* px = x   + rowo;
            const float* pp = pos + rowo;
            if (full) {
                const float2 xlo = *(const float2*)(px);
                const float2 xhi = *(const float2*)(px + 2);
                const float2 plo = *(const float2*)(pp);
                const float2 phi = *(const float2*)(pp + 2);
                vx[p][ci][0] = xlo.x; vx[p][ci][1] = xlo.y;
                vx[p][ci][2] = xhi.x; vx[p][ci][3] = xhi.y;
                vp[p][ci][0] = plo.x; vp[p][ci][1] = plo.y;
                vp[p][ci][2] = phi.x; vp[p][ci][3] = phi.y;
            } else {
#pragma unroll
                for (int si = 0; si < 4; ++si) {
                    const bool ok = (sg + si) < TOT_S;
                    vx[p][ci][si] = ok ? px[si] : 0.f;
                    vp[p][ci][si] = ok ? pp[si] : 0.f;
                }
            }
        }
    }

    const int w    = tid >> 6;
    const int lane = tid & 63;
    const int c8   = (lane & 7) * 8;

#pragma unroll
    for (int p = 0; p < 2; ++p) {
        if (p) __syncthreads();   // previous pass's LDS reads done

        // ---- write pass-p data to LDS, s-major rows (u16x4 = 8B per write)
#pragma unroll
        for (int si = 0; si < 4; ++si) {
            u16x4 wx, wp;
#pragma unroll
            for (int ci = 0; ci < 4; ++ci) {
                wx[ci] = f2bf(vx[p][ci][si]);
                wp[ci] = mk[p][si] ? (unsigned short)0
                                   : f2bf(vx[p][ci][si] + vp[p][ci][si]);
            }
            *(u16x4*)&lx[(s0 + si) * CT_P + c0] = wx;
            *(u16x4*)&lp[(s0 + si) * CT_P + c0] = wp;
        }

        __syncthreads();

        // ---- store: wave w handles rows [w*16, w*16+16); 8 lanes per row
#pragma unroll
        for (int t = 0; t < 2; ++t) {
            const int sl = w * 16 + t * 8 + (lane >> 3);
            const int s  = sb + p * 64 + sl;
            if (s >= TOT_S) continue;
            const size_t o = ((size_t)n * TOT_S + s) * CCH + cb + c8;

            const u16x4 a0 = *(const u16x4*)&lx[sl * CT_P + c8];
            const u16x4 a1 = *(const u16x4*)&lx[sl * CT_P + c8 + 4];
            u16x8 ox;
            ox[0] = a0[0]; ox[1] = a0[1]; ox[2] = a0[2]; ox[3] = a0[3];
            ox[4] = a1[0]; ox[5] = a1[1]; ox[6] = a1[2]; ox[7] = a1[3];
            *(u16x8*)(xbt + o) = ox;

            const u16x4 b0 = *(const u16x4*)&lp[sl * CT_P + c8];
            const u16x4 b1 = *(const u16x4*)&lp[sl * CT_P + c8 + 4];
            u16x8 op;
            op[0] = b0[0]; op[1] = b0[1]; op[2] = b0[2]; op[3] = b0[3];
            op[4] = b1[0]; op[5] = b1[1]; op[6] = b1[2]; op[7] = b1[3];
            *(u16x8*)(xpbt + o) = op;
        }
    }
}

// ---------------------------------------------------------------------------
// MFMA GEMM 1 (register-prefetch pipelined, BK=32)
// ---------------------------------------------------------------------------
__global__ __launch_bounds__(256)
void gemm_value_mfma(const unsigned short* __restrict__ Wb,
                     const unsigned short* __restrict__ Act,
                     const float* __restrict__ bv,
                     const unsigned char* __restrict__ mask,
                     unsigned short* __restrict__ valb)
{
    __shared__ unsigned short Wl[128 * PITCH];
    __shared__ unsigned short Al[128 * PITCH];
    const int n  = blockIdx.z;
    const int ob = blockIdx.y * 128;
    const int sb = blockIdx.x * 128;
    const int tid = threadIdx.x;
    const int r   = tid >> 1;
    const int seg = (tid & 1) * 16;
    const unsigned short* wsrc = Wb + ((size_t)(ob + r)) * CCH + seg;
    const int sr = min(sb + r, TOT_S - 1);
    const unsigned short* asrc = Act + ((size_t)n * TOT_S + sr) * CCH + seg;
    unsigned short* wdst = &Wl[r * PITCH + seg];
    unsigned short* adst = &Al[r * PITCH + seg];

    const int wave = tid >> 6, lane = tid & 63;
    const int m0 = (wave & 1) * 64, n0 = (wave >> 1) * 64;
    const int row16 = lane & 15, q = lane >> 4;

    u16x8 w0 = *(const u16x8*)(wsrc);
    u16x8 w1 = *(const u16x8*)(wsrc + 8);
    u16x8 a0 = *(const u16x8*)(asrc);
    u16x8 a1 = *(const u16x8*)(asrc + 8);

    f32x4 acc[4][4] = {};
    for (int k0 = 0; k0 < CCH; k0 += 32) {
        *(u16x8*)wdst = w0; *(u16x8*)(wdst + 8) = w1;
        *(u16x8*)adst = a0; *(u16x8*)(adst + 8) = a1;
        __syncthreads();
        if (k0 + 32 < CCH) {
            w0 = *(const u16x8*)(wsrc + k0 + 32);
            w1 = *(const u16x8*)(wsrc + k0 + 40);
            a0 = *(const u16x8*)(asrc + k0 + 32);
            a1 = *(const u16x8*)(asrc + k0 + 40);
        }
        short8 af[4], bfr[4];
#pragma unroll
        for (int mt = 0; mt < 4; ++mt)
            af[mt] = *(const short8*)&Wl[(m0 + mt * 16 + row16) * PITCH + q * 8];
#pragma unroll
        for (int nt = 0; nt < 4; ++nt)
            bfr[nt] = *(const short8*)&Al[(n0 + nt * 16 + row16) * PITCH + q * 8];
#pragma unroll
        for (int mt = 0; mt < 4; ++mt)
#pragma unroll
            for (int nt = 0; nt < 4; ++nt)
                acc[mt][nt] = __builtin_amdgcn_mfma_f32_16x16x32_bf16(
                    af[mt], bfr[nt], acc[mt][nt], 0, 0, 0);
        __syncthreads();
    }

#pragma unroll
    for (int nt = 0; nt < 4; ++nt) {
        const int s = sb + n0 + nt * 16 + row16;
        if (s >= TOT_S) continue;
        const float msk = mask[(size_t)n * TOT_S + s] ? 0.f : 1.f;
        unsigned short* orow = valb + ((size_t)n * TOT_S + s) * CCH + ob + m0;
#pragma unroll
        for (int mt = 0; mt < 4; ++mt) {
            const f32x4 bvv = *(const f32x4*)(bv + ob + m0 + mt * 16 + q * 4);
            const f32x4 a = acc[mt][nt];
            u16x4 ov;
            ov[0] = f2bf((a[0] + bvv[0]) * msk);
            ov[1] = f2bf((a[1] + bvv[1]) * msk);
            ov[2] = f2bf((a[2] + bvv[2]) * msk);
            ov[3] = f2bf((a[3] + bvv[3]) * msk);
            *(u16x4*)(orow + mt * 16 + q * 4) = ov;
        }
    }
}

// ---------------------------------------------------------------------------
// MFMA GEMM 2 (offsets+logits), fully static unroll.
// ---------------------------------------------------------------------------
__global__ __launch_bounds__(256)
void gemm_offw_mfma(const unsigned short* __restrict__ Wlb,
                    const unsigned short* __restrict__ Wwb,
                    const float* __restrict__ bloc, const float* __restrict__ bw,
                    const unsigned short* __restrict__ Act,
                    float* __restrict__ offw)
{
    __shared__ unsigned short Wl[128 * PITCH];
    __shared__ unsigned short Al[128 * PITCH];
    const int n  = blockIdx.z;
    const int sb = blockIdx.x * 128;
    const int tid = threadIdx.x;
    const int r   = tid >> 1;
    const int seg = (tid & 1) * 16;
    const bool wzero = (r >= 96);
    const unsigned short* wsrc =
        (r < 64) ? (Wlb + (size_t)r * CCH + seg)
                 : (Wwb + (size_t)((r < 96 ? r : 95) - 64) * CCH + seg);
    const int sr = min(sb + r, TOT_S - 1);
    const unsigned short* asrc = Act + ((size_t)n * TOT_S + sr) * CCH + seg;
    unsigned short* wdst = &Wl[r * PITCH + seg];
    unsigned short* adst = &Al[r * PITCH + seg];

    const int wave = tid >> 6, lane = tid & 63;
    const int m0 = (wave & 1) * 64, n0 = (wave >> 1) * 64;
    const int row16 = lane & 15, q = lane >> 4;

    u16x8 w0 = {}, w1 = {};
    if (!wzero) { w0 = *(const u16x8*)(wsrc); w1 = *(const u16x8*)(wsrc + 8); }
    u16x8 a0 = *(const u16x8*)(asrc);
    u16x8 a1 = *(const u16x8*)(asrc + 8);

    f32x4 acc[4][4] = {};
    for (int k0 = 0; k0 < CCH; k0 += 32) {
        *(u16x8*)wdst = w0; *(u16x8*)(wdst + 8) = w1;
        *(u16x8*)adst = a0; *(u16x8*)(adst + 8) = a1;
        __syncthreads();
        if (k0 + 32 < CCH) {
            if (!wzero) {
                w0 = *(const u16x8*)(wsrc + k0 + 32);
                w1 = *(const u16x8*)(wsrc + k0 + 40);
            }
            a0 = *(const u16x8*)(asrc + k0 + 32);
            a1 = *(const u16x8*)(asrc + k0 + 40);
        }
        short8 af[4], bfr[4];
#pragma unroll
        for (int mt = 0; mt < 4; ++mt)
            af[mt] = *(const short8*)&Wl[(m0 + mt * 16 + row16) * PITCH + q * 8];
#pragma unroll
        for (int nt = 0; nt < 4; ++nt)
            bfr[nt] = *(const short8*)&Al[(n0 + nt * 16 + row16) * PITCH + q * 8];
#pragma unroll
        for (int mt = 0; mt < 4; ++mt)
#pragma unroll
            for (int nt = 0; nt < 4; ++nt)
                acc[mt][nt] = __builtin_amdgcn_mfma_f32_16x16x32_bf16(
                    af[mt], bfr[nt], acc[mt][nt], 0, 0, 0);
        __syncthreads();
    }

#pragma unroll
    for (int nt = 0; nt < 4; ++nt) {
        const int s = sb + n0 + nt * 16 + row16;
        if (s >= TOT_S) continue;
        float* orow = offw + ((size_t)n * TOT_S + s) * 96;
#pragma unroll
        for (int mt = 0; mt < 4; ++mt) {
            const int o = m0 + mt * 16 + q * 4;
            if (o < 96) {
                const float* bsrc = (o < 64) ? (bloc + o) : (bw + o - 64);
                const f32x4 bb = *(const f32x4*)bsrc;
                f32x4 v = acc[mt][nt];
                v[0] += bb[0]; v[1] += bb[1]; v[2] += bb[2]; v[3] += bb[3];
                *(f32x4*)(orow + o) = v;
            }
        }
    }
}

// ---------------------------------------------------------------------------
// Sampling v2: ONE WAVE PER (n,s). lane -> head m = lane>>3, channels
// c = m*64 + (lane&7)*8 .. +8  (== lane*8: output row is one contiguous 1KiB
// store). 16B/lane gathers; branchless clamp + masked corner weights.
// ---------------------------------------------------------------------------
__global__ __launch_bounds__(256)
void sample_attn(const unsigned short* __restrict__ value,  // (N,S,512) bf16
                 const float* __restrict__ offw,            // (N,S,96)
                 const float* __restrict__ vsizes,
                 const float* __restrict__ vscales,
                 unsigned short* __restrict__ samp)         // (N,S,512) bf16
{
    const int lane = threadIdx.x;
    const int item = blockIdx.x * blockDim.y + threadIdx.y;
    const int total = NBATCH * TOT_S;
    if (item >= total) return;
    const int s = item % TOT_S;
    const int n = item / TOT_S;
    const int m = lane >> 3;

    // query level + pixel-center coords (wave-uniform)
    int lvl; float prex, prey;
    if (s < 10000)      { lvl = 0; const int l = s;         const int qq = l / 100; prey = qq + 0.5f; prex = (l - qq * 100) + 0.5f; }
    else if (s < 12500) { lvl = 1; const int l = s - 10000; const int qq = l / 50;  prey = qq + 0.5f; prex = (l - qq * 50)  + 0.5f; }
    else if (s < 13125) { lvl = 2; const int l = s - 12500; const int qq = l / 25;  prey = qq + 0.5f; prex = (l - qq * 25)  + 0.5f; }
    else                { lvl = 3; const int l = s - 13125; const int qq = l / 13;  prey = qq + 0.5f; prex = (l - qq * 13)  + 0.5f; }

    const float* ow = offw + ((size_t)n * TOT_S + s) * 96;

    // per-head softmax over 4 logits (replicated across the 8 lanes of a head)
    const float w0 = ow[64 + m * 4 + 0], w1 = ow[64 + m * 4 + 1];
    const float w2 = ow[64 + m * 4 + 2], w3 = ow[64 + m * 4 + 3];
    const float mx = fmaxf(fmaxf(w0, w1), fmaxf(w2, w3));
    const float e0 = expf(w0 - mx), e1 = expf(w1 - mx), e2 = expf(w2 - mx), e3 = expf(w3 - mx);
    const float inv = 1.f / (e0 + e1 + e2 + e3);
    const float wgt[4] = { e0 * inv, e1 * inv, e2 * inv, e3 * inv };

    const int HS[4]  = { 100, 50, 25, 13 };
    const int WS[4]  = { 100, 50, 25, 13 };
    const int CUR[4] = { 0, 10000, 12500, 13125 };

    const float invsx = 1.f / vsizes[((n * 4) + lvl) * 2 + 0];
    const float invsy = 1.f / vsizes[((n * 4) + lvl) * 2 + 1];
    // channel base: c = lane*8
    const unsigned short* vbase = value + (size_t)n * TOT_S * CCH + lane * 8;

    float acc[8] = {};
#pragma unroll
    for (int f = 0; f < 4; ++f) {
        const float offx = ow[(m * 4 + f) * 2 + 0];
        const float offy = ow[(m * 4 + f) * 2 + 1];
        const float scx = 2.f * vscales[((n * 4) + f) * 2 + 0] * invsx;
        const float scy = 2.f * vscales[((n * 4) + f) * 2 + 1] * invsy;
        const int Wf = WS[f], Hf = HS[f], cf = CUR[f];
        const float xi = (offx + prex) * scx * (Wf * 0.5f) - 0.5f;
        const float yi = (offy + prey) * scy * (Hf * 0.5f) - 0.5f;
        const float x0f = floorf(xi), y0f = floorf(yi);
        const float wx1 = xi - x0f, wy1 = yi - y0f;
        const float wx0 = 1.f - wx1, wy0 = 1.f - wy1;
        const int x0 = (int)x0f, y0 = (int)y0f;
        const bool xin0 = (x0 >= 0) && (x0 < Wf);
        const bool xin1 = (x0 + 1 >= 0) && (x0 + 1 < Wf);
        const bool yin0 = (y0 >= 0) && (y0 < Hf);
        const bool yin1 = (y0 + 1 >= 0) && (y0 + 1 < Hf);
        // masked corner weights (fold level weight in), clamped indices
        const float cw00 = (xin0 && yin0) ? wgt[f] * wx0 * wy0 : 0.f;
        const float cw10 = (xin1 && yin0) ? wgt[f] * wx1 * wy0 : 0.f;
        const float cw01 = (xin0 && yin1) ? wgt[f] * wx0 * wy1 : 0.f;
        const float cw11 = (xin1 && yin1) ? wgt[f] * wx1 * wy1 : 0.f;
        const int x0c = min(max(x0, 0), Wf - 1);
        const int x1c = min(max(x0 + 1, 0), Wf - 1);
        const int y0c = min(max(y0, 0), Hf - 1);
        const int y1c = min(max(y0 + 1, 0), Hf - 1);
        const unsigned short* row0 = vbase + (size_t)(cf + y0c * Wf) * CCH;
        const unsigned short* row1 = vbase + (size_t)(cf + y1c * Wf) * CCH;
        const u16x8 v00 = *(const u16x8*)(row0 + (size_t)x0c * CCH);
        const u16x8 v10 = *(const u16x8*)(row0 + (size_t)x1c * CCH);
        const u16x8 v01 = *(const u16x8*)(row1 + (size_t)x0c * CCH);
        const u16x8 v11 = *(const u16x8*)(row1 + (size_t)x1c * CCH);
#pragma unroll
        for (int j = 0; j < 8; ++j) {
            acc[j] += cw00 * bf2f(v00[j]) + cw10 * bf2f(v10[j])
                    + cw01 * bf2f(v01[j]) + cw11 * bf2f(v11[j]);
        }
    }

    u16x8 ov;
#pragma unroll
    for (int j = 0; j < 8; ++j) ov[j] = f2bf(acc[j]);
    *(u16x8*)(samp + ((size_t)n * TOT_S + s) * CCH + lane * 8) = ov;
}

// ---------------------------------------------------------------------------
// MFMA GEMM 3: out[n][o][s] = (sum_c Wo[o][c]*samp[s][c] + bo[o]) * scale[o]
// ---------------------------------------------------------------------------
__global__ __launch_bounds__(256)
void gemm_out_mfma(const unsigned short* __restrict__ Wob,
                   const unsigned short* __restrict__ Sampb,
                   const float* __restrict__ bo, const float* __restrict__ scale,
                   float* __restrict__ out)
{
    __shared__ unsigned short Sl[128 * PITCH];
    __shared__ unsigned short Wl[128 * PITCH];
    const int n  = blockIdx.z;
    const int ob = blockIdx.y * 128;
    const int sb = blockIdx.x * 128;
    const int tid = threadIdx.x;
    const int r   = tid >> 1;
    const int seg = (tid & 1) * 16;
    const int sr = min(sb + r, TOT_S - 1);
    const unsigned short* ssrc = Sampb + ((size_t)n * TOT_S + sr) * CCH + seg;
    const unsigned short* wsrc = Wob + ((size_t)(ob + r)) * CCH + seg;
    unsigned short* sdst = &Sl[r * PITCH + seg];
    unsigned short* wdst = &Wl[r * PITCH + seg];

    const int wave = tid >> 6, lane = tid & 63;
    const int m0 = (wave & 1) * 64, n0 = (wave >> 1) * 64;
    const int row16 = lane & 15, q = lane >> 4;

    u16x8 s0v = *(const u16x8*)(ssrc);
    u16x8 s1v = *(const u16x8*)(ssrc + 8);
    u16x8 w0v = *(const u16x8*)(wsrc);
    u16x8 w1v = *(const u16x8*)(wsrc + 8);

    f32x4 acc[4][4] = {};
    for (int k0 = 0; k0 < CCH; k0 += 32) {
        *(u16x8*)sdst = s0v; *(u16x8*)(sdst + 8) = s1v;
        *(u16x8*)wdst = w0v; *(u16x8*)(wdst + 8) = w1v;
        __syncthreads();
        if (k0 + 32 < CCH) {
            s0v = *(const u16x8*)(ssrc + k0 + 32);
            s1v = *(const u16x8*)(ssrc + k0 + 40);
            w0v = *(const u16x8*)(wsrc + k0 + 32);
            w1v = *(const u16x8*)(wsrc + k0 + 40);
        }
        short8 af[4], bfr[4];
#pragma unroll
        for (int mt = 0; mt < 4; ++mt)
            af[mt] = *(const short8*)&Sl[(m0 + mt * 16 + row16) * PITCH + q * 8];
#pragma unroll
        for (int nt = 0; nt < 4; ++nt)
            bfr[nt] = *(const short8*)&Wl[(n0 + nt * 16 + row16) * PITCH + q * 8];
#pragma unroll
        for (int mt = 0; mt < 4; ++mt)
#pragma unroll
            for (int nt = 0; nt < 4; ++nt)
                acc[mt][nt] = __builtin_amdgcn_mfma_f32_16x16x32_bf16(
                    af[mt], bfr[nt], acc[mt][nt], 0, 0, 0);
        __syncthreads();
    }

#pragma unroll
    for (int nt = 0; nt < 4; ++nt) {
        const int o = ob + n0 + nt * 16 + row16;
        const float bo_ = bo[o];
        const float sc_ = scale[o];
        float* orow = out + ((size_t)n * CCH + o) * (size_t)TOT_S;
#pragma unroll
        for (int mt = 0; mt < 4; ++mt) {
            const int s0 = sb + m0 + mt * 16 + q * 4;
            const f32x4 a = acc[mt][nt];
            if (s0 + 3 < TOT_S) {
                float2 v0 = make_float2((a[0] + bo_) * sc_, (a[1] + bo_) * sc_);
                float2 v1 = make_float2((a[2] + bo_) * sc_, (a[3] + bo_) * sc_);
                *(float2*)(orow + s0) = v0;
                *(float2*)(orow + s0 + 2) = v1;
            } else {
                for (int i = 0; i < 4; ++i)
                    if (s0 + i < TOT_S) orow[s0 + i] = (a[i] + bo_) * sc_;
            }
        }
    }
}

// ---------------------------------------------------------------------------
extern "C" void kernel_launch(void* const* d_in, const int* in_sizes, int n_in,
                              void* d_out, int out_size, void* d_ws, size_t ws_size,
                              hipStream_t stream)
{
    const float* x     = (const float*)d_in[0];
    const float* pos   = (const float*)d_in[1];
    const unsigned char* mask = (const unsigned char*)d_in[2];
    const float* vsz   = (const float*)d_in[3];
    const float* vsc   = (const float*)d_in[4];
    const float* Wv    = (const float*)d_in[5];
    const float* bv    = (const float*)d_in[6];
    const float* Wloc  = (const float*)d_in[7];
    const float* bloc  = (const float*)d_in[8];
    const float* Ww    = (const float*)d_in[9];
    const float* bw    = (const float*)d_in[10];
    const float* Wo    = (const float*)d_in[11];
    const float* bo    = (const float*)d_in[12];
    const float* scale = (const float*)d_in[13];
    float* out = (float*)d_out;

    const size_t SC = (size_t)TOT_S * CCH;
    unsigned short* valb  = (unsigned short*)d_ws;
    unsigned short* sampb = valb  + 2 * SC;
    unsigned short* xbt   = sampb + 2 * SC;
    unsigned short* xpbt  = xbt   + 2 * SC;
    float* offw = (float*)(xpbt + 2 * SC);
    unsigned short* wvb = (unsigned short*)(offw + 2 * (size_t)TOT_S * 96);
    unsigned short* wob = wvb + 512 * 512;
    unsigned short* wlb = wob + 512 * 512;
    unsigned short* wwb = wlb + 64 * 512;

    cast_f32_bf16<<<256, 256, 0, stream>>>(Wv,   wvb, 512 * 512 / 4);
    cast_f32_bf16<<<256, 256, 0, stream>>>(Wo,   wob, 512 * 512 / 4);
    cast_f32_bf16<<<32,  256, 0, stream>>>(Wloc, wlb, 64 * 512 / 4);
    cast_f32_bf16<<<16,  256, 0, stream>>>(Ww,   wwb, 32 * 512 / 4);

    cast_transpose<<<dim3((TOT_S + 127) / 128, CCH / 64, NBATCH), 256, 0, stream>>>(
        x, pos, mask, xbt, xpbt);

    const int sTiles = (TOT_S + 127) / 128;  // 104

    gemm_value_mfma<<<dim3(sTiles, CCH / 128, NBATCH), 256, 0, stream>>>(
        wvb, xbt, bv, mask, valb);
    gemm_offw_mfma<<<dim3(sTiles, 1, NBATCH), 256, 0, stream>>>(
        wlb, wwb, bloc, bw, xpbt, offw);

    const int items = NBATCH * TOT_S;   // one wave per (n,s) now
    sample_attn<<<(items + 3) / 4, dim3(64, 4), 0, stream>>>(valb, offw, vsz, vsc, sampb);

    gemm_out_mfma<<<dim3(sTiles, CCH / 128, NBATCH), 256, 0, stream>>>(
        wob, sampb, bo, scale, out);
}

// Round 5
// 291.115 us; speedup vs baseline: 1.0586x; 1.0586x over previous
//
#include <hip/hip_runtime.h>
#include <math.h>

#define TOT_S   13294
#define NBATCH  2
#define CCH     512
#define MHEAD   8
#define PITCH   40   // LDS row pitch in bf16 elems (32 + 8 pad -> 80B)

typedef short     short8  __attribute__((ext_vector_type(8)));
typedef float     f32x4   __attribute__((ext_vector_type(4)));
typedef unsigned short u16x8 __attribute__((ext_vector_type(8)));
typedef unsigned short u16x4 __attribute__((ext_vector_type(4)));

__device__ __forceinline__ unsigned short f2bf(float f) {
    union { float f; unsigned int u; } v; v.f = f;
    unsigned int r = v.u + 0x7fffu + ((v.u >> 16) & 1u);   // RNE
    return (unsigned short)(r >> 16);
}
__device__ __forceinline__ float bf2f(unsigned short h) {
    union { unsigned int u; float f; } v; v.u = ((unsigned int)h) << 16;
    return v.f;
}

// ---------------------------------------------------------------------------
__global__ void cast_f32_bf16(const float* __restrict__ src,
                              unsigned short* __restrict__ dst, int n4)
{
    const int i = blockIdx.x * blockDim.x + threadIdx.x;
    if (i < n4) {
        const float4 v = *(const float4*)(src + (size_t)i * 4);
        u16x4 o;
        o[0] = f2bf(v.x); o[1] = f2bf(v.y); o[2] = f2bf(v.z); o[3] = f2bf(v.w);
        *(u16x4*)(dst + (size_t)i * 4) = o;
    }
}

// ---------------------------------------------------------------------------
// MFMA GEMM 1 (fused transpose staging): Act comes straight from x (f32,
// (c,s) layout). Per k-tile each thread loads 8 coalesced float2 along s
// (wave = 4 c-rows x 128B contiguous), converts to bf16, packs the c-pair
// into a u32 and writes the SAME [s][k] LDS layout the MFMA frags read.
// ---------------------------------------------------------------------------
__global__ __launch_bounds__(256)
void gemm_value_mfma(const unsigned short* __restrict__ Wb,
                     const float* __restrict__ x,
                     const float* __restrict__ bv,
                     const unsigned char* __restrict__ mask,
                     unsigned short* __restrict__ valb)
{
    __shared__ unsigned short Wl[128 * PITCH];
    __shared__ unsigned short Al[128 * PITCH];
    const int n  = blockIdx.z;
    const int ob = blockIdx.y * 128;
    const int sb = blockIdx.x * 128;
    const int tid = threadIdx.x;

    // ---- W staging mapping (unchanged)
    const int r   = tid >> 1;
    const int seg = (tid & 1) * 16;
    const unsigned short* wsrc = Wb + ((size_t)(ob + r)) * CCH + seg;
    unsigned short* wdst = &Wl[r * PITCH + seg];

    // ---- Act transposed-staging mapping
    const int sp   = tid & 15;    // s-pair id: s = 2*sp + 32*j + i
    const int cpid = tid >> 4;    // c-pair id: k_local = 2*cpid + cc
    const size_t XLIM = (size_t)NBATCH * CCH * TOT_S - 2;

    const int wave = tid >> 6, lane = tid & 63;
    const int m0 = (wave & 1) * 64, n0 = (wave >> 1) * 64;
    const int row16 = lane & 15, q = lane >> 4;

    u16x8 w0 = *(const u16x8*)(wsrc);
    u16x8 w1 = *(const u16x8*)(wsrc + 8);
    float2 ax[2][4];
#pragma unroll
    for (int cc = 0; cc < 2; ++cc)
#pragma unroll
        for (int j = 0; j < 4; ++j) {
            size_t off = ((size_t)n * CCH + 2 * cpid + cc) * TOT_S
                       + sb + 2 * sp + 32 * j;
            off = off > XLIM ? XLIM : off;
            ax[cc][j] = *(const float2*)(x + off);
        }

    f32x4 acc[4][4] = {};
    for (int k0 = 0; k0 < CCH; k0 += 32) {
        *(u16x8*)wdst = w0; *(u16x8*)(wdst + 8) = w1;
#pragma unroll
        for (int j = 0; j < 4; ++j)
#pragma unroll
            for (int i = 0; i < 2; ++i) {
                const int s = 2 * sp + 32 * j + i;
                const float lo = i ? ax[0][j].y : ax[0][j].x;
                const float hi = i ? ax[1][j].y : ax[1][j].x;
                const unsigned int pk =
                    (unsigned int)f2bf(lo) | ((unsigned int)f2bf(hi) << 16);
                *(unsigned int*)&Al[(size_t)s * PITCH + 2 * cpid] = pk;
            }
        __syncthreads();
        if (k0 + 32 < CCH) {
            w0 = *(const u16x8*)(wsrc + k0 + 32);
            w1 = *(const u16x8*)(wsrc + k0 + 40);
#pragma unroll
            for (int cc = 0; cc < 2; ++cc)
#pragma unroll
                for (int j = 0; j < 4; ++j) {
                    size_t off = ((size_t)n * CCH + k0 + 32 + 2 * cpid + cc) * TOT_S
                               + sb + 2 * sp + 32 * j;
                    off = off > XLIM ? XLIM : off;
                    ax[cc][j] = *(const float2*)(x + off);
                }
        }
        short8 af[4], bfr[4];
#pragma unroll
        for (int mt = 0; mt < 4; ++mt)
            af[mt] = *(const short8*)&Wl[(m0 + mt * 16 + row16) * PITCH + q * 8];
#pragma unroll
        for (int nt = 0; nt < 4; ++nt)
            bfr[nt] = *(const short8*)&Al[(n0 + nt * 16 + row16) * PITCH + q * 8];
#pragma unroll
        for (int mt = 0; mt < 4; ++mt)
#pragma unroll
            for (int nt = 0; nt < 4; ++nt)
                acc[mt][nt] = __builtin_amdgcn_mfma_f32_16x16x32_bf16(
                    af[mt], bfr[nt], acc[mt][nt], 0, 0, 0);
        __syncthreads();
    }

#pragma unroll
    for (int nt = 0; nt < 4; ++nt) {
        const int s = sb + n0 + nt * 16 + row16;
        if (s >= TOT_S) continue;
        const float msk = mask[(size_t)n * TOT_S + s] ? 0.f : 1.f;
        unsigned short* orow = valb + ((size_t)n * TOT_S + s) * CCH + ob + m0;
#pragma unroll
        for (int mt = 0; mt < 4; ++mt) {
            const f32x4 bvv = *(const f32x4*)(bv + ob + m0 + mt * 16 + q * 4);
            const f32x4 a = acc[mt][nt];
            u16x4 ov;
            ov[0] = f2bf((a[0] + bvv[0]) * msk);
            ov[1] = f2bf((a[1] + bvv[1]) * msk);
            ov[2] = f2bf((a[2] + bvv[2]) * msk);
            ov[3] = f2bf((a[3] + bvv[3]) * msk);
            *(u16x4*)(orow + mt * 16 + q * 4) = ov;
        }
    }
}

// ---------------------------------------------------------------------------
// MFMA GEMM 2 (offsets+logits), fused transpose staging of (x+pos)*~mask.
// ---------------------------------------------------------------------------
__global__ __launch_bounds__(256)
void gemm_offw_mfma(const unsigned short* __restrict__ Wlb,
                    const unsigned short* __restrict__ Wwb,
                    const float* __restrict__ bloc, const float* __restrict__ bw,
                    const float* __restrict__ x, const float* __restrict__ pos,
                    const unsigned char* __restrict__ mask,
                    float* __restrict__ offw)
{
    __shared__ unsigned short Wl[128 * PITCH];
    __shared__ unsigned short Al[128 * PITCH];
    const int n  = blockIdx.z;
    const int sb = blockIdx.x * 128;
    const int tid = threadIdx.x;

    // ---- W staging (unchanged)
    const int r   = tid >> 1;
    const int seg = (tid & 1) * 16;
    const bool wzero = (r >= 96);
    const unsigned short* wsrc =
        (r < 64) ? (Wlb + (size_t)r * CCH + seg)
                 : (Wwb + (size_t)((r < 96 ? r : 95) - 64) * CCH + seg);
    unsigned short* wdst = &Wl[r * PITCH + seg];

    // ---- Act transposed-staging mapping
    const int sp   = tid & 15;
    const int cpid = tid >> 4;
    const size_t XLIM = (size_t)NBATCH * CCH * TOT_S - 2;
    float mkm[8];
#pragma unroll
    for (int j = 0; j < 4; ++j)
#pragma unroll
        for (int i = 0; i < 2; ++i) {
            const int s = sb + 2 * sp + 32 * j + i;
            const int sc = s < TOT_S ? s : TOT_S - 1;
            mkm[j * 2 + i] = mask[(size_t)n * TOT_S + sc] ? 0.f : 1.f;
        }

    const int wave = tid >> 6, lane = tid & 63;
    const int m0 = (wave & 1) * 64, n0 = (wave >> 1) * 64;
    const int row16 = lane & 15, q = lane >> 4;

    u16x8 w0 = {}, w1 = {};
    if (!wzero) { w0 = *(const u16x8*)(wsrc); w1 = *(const u16x8*)(wsrc + 8); }
    float2 ax[2][4], ap[2][4];
#pragma unroll
    for (int cc = 0; cc < 2; ++cc)
#pragma unroll
        for (int j = 0; j < 4; ++j) {
            size_t off = ((size_t)n * CCH + 2 * cpid + cc) * TOT_S
                       + sb + 2 * sp + 32 * j;
            off = off > XLIM ? XLIM : off;
            ax[cc][j] = *(const float2*)(x + off);
            ap[cc][j] = *(const float2*)(pos + off);
        }

    f32x4 acc[4][4] = {};
    for (int k0 = 0; k0 < CCH; k0 += 32) {
        *(u16x8*)wdst = w0; *(u16x8*)(wdst + 8) = w1;
#pragma unroll
        for (int j = 0; j < 4; ++j)
#pragma unroll
            for (int i = 0; i < 2; ++i) {
                const int s = 2 * sp + 32 * j + i;
                const float lo = (i ? ax[0][j].y + ap[0][j].y
                                    : ax[0][j].x + ap[0][j].x) * mkm[j * 2 + i];
                const float hi = (i ? ax[1][j].y + ap[1][j].y
                                    : ax[1][j].x + ap[1][j].x) * mkm[j * 2 + i];
                const unsigned int pk =
                    (unsigned int)f2bf(lo) | ((unsigned int)f2bf(hi) << 16);
                *(unsigned int*)&Al[(size_t)s * PITCH + 2 * cpid] = pk;
            }
        __syncthreads();
        if (k0 + 32 < CCH) {
            if (!wzero) {
                w0 = *(const u16x8*)(wsrc + k0 + 32);
                w1 = *(const u16x8*)(wsrc + k0 + 40);
            }
#pragma unroll
            for (int cc = 0; cc < 2; ++cc)
#pragma unroll
                for (int j = 0; j < 4; ++j) {
                    size_t off = ((size_t)n * CCH + k0 + 32 + 2 * cpid + cc) * TOT_S
                               + sb + 2 * sp + 32 * j;
                    off = off > XLIM ? XLIM : off;
                    ax[cc][j] = *(const float2*)(x + off);
                    ap[cc][j] = *(const float2*)(pos + off);
                }
        }
        short8 af[4], bfr[4];
#pragma unroll
        for (int mt = 0; mt < 4; ++mt)
            af[mt] = *(const short8*)&Wl[(m0 + mt * 16 + row16) * PITCH + q * 8];
#pragma unroll
        for (int nt = 0; nt < 4; ++nt)
            bfr[nt] = *(const short8*)&Al[(n0 + nt * 16 + row16) * PITCH + q * 8];
#pragma unroll
        for (int mt = 0; mt < 4; ++mt)
#pragma unroll
            for (int nt = 0; nt < 4; ++nt)
                acc[mt][nt] = __builtin_amdgcn_mfma_f32_16x16x32_bf16(
                    af[mt], bfr[nt], acc[mt][nt], 0, 0, 0);
        __syncthreads();
    }

#pragma unroll
    for (int nt = 0; nt < 4; ++nt) {
        const int s = sb + n0 + nt * 16 + row16;
        if (s >= TOT_S) continue;
        float* orow = offw + ((size_t)n * TOT_S + s) * 96;
#pragma unroll
        for (int mt = 0; mt < 4; ++mt) {
            const int o = m0 + mt * 16 + q * 4;
            if (o < 96) {
                const float* bsrc = (o < 64) ? (bloc + o) : (bw + o - 64);
                const f32x4 bb = *(const f32x4*)bsrc;
                f32x4 v = acc[mt][nt];
                v[0] += bb[0]; v[1] += bb[1]; v[2] += bb[2]; v[3] += bb[3];
                *(f32x4*)(orow + o) = v;
            }
        }
    }
}

// ---------------------------------------------------------------------------
// Sampling v2: ONE WAVE PER (n,s). lane -> head m = lane>>3, channels
// c = m*64 + (lane&7)*8 .. +8  (== lane*8: output row is one contiguous 1KiB
// store). 16B/lane gathers; branchless clamp + masked corner weights.
// ---------------------------------------------------------------------------
__global__ __launch_bounds__(256)
void sample_attn(const unsigned short* __restrict__ value,  // (N,S,512) bf16
                 const float* __restrict__ offw,            // (N,S,96)
                 const float* __restrict__ vsizes,
                 const float* __restrict__ vscales,
                 unsigned short* __restrict__ samp)         // (N,S,512) bf16
{
    const int lane = threadIdx.x;
    const int item = blockIdx.x * blockDim.y + threadIdx.y;
    const int total = NBATCH * TOT_S;
    if (item >= total) return;
    const int s = item % TOT_S;
    const int n = item / TOT_S;
    const int m = lane >> 3;

    // query level + pixel-center coords (wave-uniform)
    int lvl; float prex, prey;
    if (s < 10000)      { lvl = 0; const int l = s;         const int qq = l / 100; prey = qq + 0.5f; prex = (l - qq * 100) + 0.5f; }
    else if (s < 12500) { lvl = 1; const int l = s - 10000; const int qq = l / 50;  prey = qq + 0.5f; prex = (l - qq * 50)  + 0.5f; }
    else if (s < 13125) { lvl = 2; const int l = s - 12500; const int qq = l / 25;  prey = qq + 0.5f; prex = (l - qq * 25)  + 0.5f; }
    else                { lvl = 3; const int l = s - 13125; const int qq = l / 13;  prey = qq + 0.5f; prex = (l - qq * 13)  + 0.5f; }

    const float* ow = offw + ((size_t)n * TOT_S + s) * 96;

    // per-head softmax over 4 logits (replicated across the 8 lanes of a head)
    const float w0 = ow[64 + m * 4 + 0], w1 = ow[64 + m * 4 + 1];
    const float w2 = ow[64 + m * 4 + 2], w3 = ow[64 + m * 4 + 3];
    const float mx = fmaxf(fmaxf(w0, w1), fmaxf(w2, w3));
    const float e0 = expf(w0 - mx), e1 = expf(w1 - mx), e2 = expf(w2 - mx), e3 = expf(w3 - mx);
    const float inv = 1.f / (e0 + e1 + e2 + e3);
    const float wgt[4] = { e0 * inv, e1 * inv, e2 * inv, e3 * inv };

    const int HS[4]  = { 100, 50, 25, 13 };
    const int WS[4]  = { 100, 50, 25, 13 };
    const int CUR[4] = { 0, 10000, 12500, 13125 };

    const float invsx = 1.f / vsizes[((n * 4) + lvl) * 2 + 0];
    const float invsy = 1.f / vsizes[((n * 4) + lvl) * 2 + 1];
    // channel base: c = lane*8
    const unsigned short* vbase = value + (size_t)n * TOT_S * CCH + lane * 8;

    float acc[8] = {};
#pragma unroll
    for (int f = 0; f < 4; ++f) {
        const float offx = ow[(m * 4 + f) * 2 + 0];
        const float offy = ow[(m * 4 + f) * 2 + 1];
        const float scx = 2.f * vscales[((n * 4) + f) * 2 + 0] * invsx;
        const float scy = 2.f * vscales[((n * 4) + f) * 2 + 1] * invsy;
        const int Wf = WS[f], Hf = HS[f], cf = CUR[f];
        const float xi = (offx + prex) * scx * (Wf * 0.5f) - 0.5f;
        const float yi = (offy + prey) * scy * (Hf * 0.5f) - 0.5f;
        const float x0f = floorf(xi), y0f = floorf(yi);
        const float wx1 = xi - x0f, wy1 = yi - y0f;
        const float wx0 = 1.f - wx1, wy0 = 1.f - wy1;
        const int x0 = (int)x0f, y0 = (int)y0f;
        const bool xin0 = (x0 >= 0) && (x0 < Wf);
        const bool xin1 = (x0 + 1 >= 0) && (x0 + 1 < Wf);
        const bool yin0 = (y0 >= 0) && (y0 < Hf);
        const bool yin1 = (y0 + 1 >= 0) && (y0 + 1 < Hf);
        // masked corner weights (fold level weight in), clamped indices
        const float cw00 = (xin0 && yin0) ? wgt[f] * wx0 * wy0 : 0.f;
        const float cw10 = (xin1 && yin0) ? wgt[f] * wx1 * wy0 : 0.f;
        const float cw01 = (xin0 && yin1) ? wgt[f] * wx0 * wy1 : 0.f;
        const float cw11 = (xin1 && yin1) ? wgt[f] * wx1 * wy1 : 0.f;
        const int x0c = min(max(x0, 0), Wf - 1);
        const int x1c = min(max(x0 + 1, 0), Wf - 1);
        const int y0c = min(max(y0, 0), Hf - 1);
        const int y1c = min(max(y0 + 1, 0), Hf - 1);
        const unsigned short* row0 = vbase + (size_t)(cf + y0c * Wf) * CCH;
        const unsigned short* row1 = vbase + (size_t)(cf + y1c * Wf) * CCH;
        const u16x8 v00 = *(const u16x8*)(row0 + (size_t)x0c * CCH);
        const u16x8 v10 = *(const u16x8*)(row0 + (size_t)x1c * CCH);
        const u16x8 v01 = *(const u16x8*)(row1 + (size_t)x0c * CCH);
        const u16x8 v11 = *(const u16x8*)(row1 + (size_t)x1c * CCH);
#pragma unroll
        for (int j = 0; j < 8; ++j) {
            acc[j] += cw00 * bf2f(v00[j]) + cw10 * bf2f(v10[j])
                    + cw01 * bf2f(v01[j]) + cw11 * bf2f(v11[j]);
        }
    }

    u16x8 ov;
#pragma unroll
    for (int j = 0; j < 8; ++j) ov[j] = f2bf(acc[j]);
    *(u16x8*)(samp + ((size_t)n * TOT_S + s) * CCH + lane * 8) = ov;
}

// ---------------------------------------------------------------------------
// MFMA GEMM 3: out[n][o][s] = (sum_c Wo[o][c]*samp[s][c] + bo[o]) * scale[o]
// ---------------------------------------------------------------------------
__global__ __launch_bounds__(256)
void gemm_out_mfma(const unsigned short* __restrict__ Wob,
                   const unsigned short* __restrict__ Sampb,
                   const float* __restrict__ bo, const float* __restrict__ scale,
                   float* __restrict__ out)
{
    __shared__ unsigned short Sl[128 * PITCH];
    __shared__ unsigned short Wl[128 * PITCH];
    const int n  = blockIdx.z;
    const int ob = blockIdx.y * 128;
    const int sb = blockIdx.x * 128;
    const int tid = threadIdx.x;
    const int r   = tid >> 1;
    const int seg = (tid & 1) * 16;
    const int sr = min(sb + r, TOT_S - 1);
    const unsigned short* ssrc = Sampb + ((size_t)n * TOT_S + sr) * CCH + seg;
    const unsigned short* wsrc = Wob + ((size_t)(ob + r)) * CCH + seg;
    unsigned short* sdst = &Sl[r * PITCH + seg];
    unsigned short* wdst = &Wl[r * PITCH + seg];

    const int wave = tid >> 6, lane = tid & 63;
    const int m0 = (wave & 1) * 64, n0 = (wave >> 1) * 64;
    const int row16 = lane & 15, q = lane >> 4;

    u16x8 s0v = *(const u16x8*)(ssrc);
    u16x8 s1v = *(const u16x8*)(ssrc + 8);
    u16x8 w0v = *(const u16x8*)(wsrc);
    u16x8 w1v = *(const u16x8*)(wsrc + 8);

    f32x4 acc[4][4] = {};
    for (int k0 = 0; k0 < CCH; k0 += 32) {
        *(u16x8*)sdst = s0v; *(u16x8*)(sdst + 8) = s1v;
        *(u16x8*)wdst = w0v; *(u16x8*)(wdst + 8) = w1v;
        __syncthreads();
        if (k0 + 32 < CCH) {
            s0v = *(const u16x8*)(ssrc + k0 + 32);
            s1v = *(const u16x8*)(ssrc + k0 + 40);
            w0v = *(const u16x8*)(wsrc + k0 + 32);
            w1v = *(const u16x8*)(wsrc + k0 + 40);
        }
        short8 af[4], bfr[4];
#pragma unroll
        for (int mt = 0; mt < 4; ++mt)
            af[mt] = *(const short8*)&Sl[(m0 + mt * 16 + row16) * PITCH + q * 8];
#pragma unroll
        for (int nt = 0; nt < 4; ++nt)
            bfr[nt] = *(const short8*)&Wl[(n0 + nt * 16 + row16) * PITCH + q * 8];
#pragma unroll
        for (int mt = 0; mt < 4; ++mt)
#pragma unroll
            for (int nt = 0; nt < 4; ++nt)
                acc[mt][nt] = __builtin_amdgcn_mfma_f32_16x16x32_bf16(
                    af[mt], bfr[nt], acc[mt][nt], 0, 0, 0);
        __syncthreads();
    }

#pragma unroll
    for (int nt = 0; nt < 4; ++nt) {
        const int o = ob + n0 + nt * 16 + row16;
        const float bo_ = bo[o];
        const float sc_ = scale[o];
        float* orow = out + ((size_t)n * CCH + o) * (size_t)TOT_S;
#pragma unroll
        for (int mt = 0; mt < 4; ++mt) {
            const int s0 = sb + m0 + mt * 16 + q * 4;
            const f32x4 a = acc[mt][nt];
            if (s0 + 3 < TOT_S) {
                float2 v0 = make_float2((a[0] + bo_) * sc_, (a[1] + bo_) * sc_);
                float2 v1 = make_float2((a[2] + bo_) * sc_, (a[3] + bo_) * sc_);
                *(float2*)(orow + s0) = v0;
                *(float2*)(orow + s0 + 2) = v1;
            } else {
                for (int i = 0; i < 4; ++i)
                    if (s0 + i < TOT_S) orow[s0 + i] = (a[i] + bo_) * sc_;
            }
        }
    }
}

// ---------------------------------------------------------------------------
extern "C" void kernel_launch(void* const* d_in, const int* in_sizes, int n_in,
                              void* d_out, int out_size, void* d_ws, size_t ws_size,
                              hipStream_t stream)
{
    const float* x     = (const float*)d_in[0];
    const float* pos   = (const float*)d_in[1];
    const unsigned char* mask = (const unsigned char*)d_in[2];
    const float* vsz   = (const float*)d_in[3];
    const float* vsc   = (const float*)d_in[4];
    const float* Wv    = (const float*)d_in[5];
    const float* bv    = (const float*)d_in[6];
    const float* Wloc  = (const float*)d_in[7];
    const float* bloc  = (const float*)d_in[8];
    const float* Ww    = (const float*)d_in[9];
    const float* bw    = (const float*)d_in[10];
    const float* Wo    = (const float*)d_in[11];
    const float* bo    = (const float*)d_in[12];
    const float* scale = (const float*)d_in[13];
    float* out = (float*)d_out;

    const size_t SC = (size_t)TOT_S * CCH;
    unsigned short* valb  = (unsigned short*)d_ws;
    unsigned short* sampb = valb  + 2 * SC;
    float* offw = (float*)(sampb + 2 * SC);
    unsigned short* wvb = (unsigned short*)(offw + 2 * (size_t)TOT_S * 96);
    unsigned short* wob = wvb + 512 * 512;
    unsigned short* wlb = wob + 512 * 512;
    unsigned short* wwb = wlb + 64 * 512;

    cast_f32_bf16<<<256, 256, 0, stream>>>(Wv,   wvb, 512 * 512 / 4);
    cast_f32_bf16<<<256, 256, 0, stream>>>(Wo,   wob, 512 * 512 / 4);
    cast_f32_bf16<<<32,  256, 0, stream>>>(Wloc, wlb, 64 * 512 / 4);
    cast_f32_bf16<<<16,  256, 0, stream>>>(Ww,   wwb, 32 * 512 / 4);

    const int sTiles = (TOT_S + 127) / 128;  // 104

    gemm_value_mfma<<<dim3(sTiles, CCH / 128, NBATCH), 256, 0, stream>>>(
        wvb, x, bv, mask, valb);
    gemm_offw_mfma<<<dim3(sTiles, 1, NBATCH), 256, 0, stream>>>(
        wlb, wwb, bloc, bw, x, pos, mask, offw);

    const int items = NBATCH * TOT_S;   // one wave per (n,s)
    sample_attn<<<(items + 3) / 4, dim3(64, 4), 0, stream>>>(valb, offw, vsz, vsc, sampb);

    gemm_out_mfma<<<dim3(sTiles, CCH / 128, NBATCH), 256, 0, stream>>>(
        wob, sampb, bo, scale, out);
}

// Round 6
// 286.963 us; speedup vs baseline: 1.0740x; 1.0145x over previous
//
#include <hip/hip_runtime.h>
#include <math.h>

#define TOT_S   13294
#define NBATCH  2
#define CCH     512
#define MHEAD   8
#define PITCH   40   // LDS row pitch in bf16 elems (32 + 8 pad -> 80B)

typedef short     short8  __attribute__((ext_vector_type(8)));
typedef float     f32x4   __attribute__((ext_vector_type(4)));
typedef unsigned short u16x8 __attribute__((ext_vector_type(8)));
typedef unsigned short u16x4 __attribute__((ext_vector_type(4)));

__device__ __forceinline__ unsigned short f2bf(float f) {
    union { float f; unsigned int u; } v; v.f = f;
    unsigned int r = v.u + 0x7fffu + ((v.u >> 16) & 1u);   // RNE
    return (unsigned short)(r >> 16);
}
__device__ __forceinline__ float bf2f(unsigned short h) {
    union { unsigned int u; float f; } v; v.u = ((unsigned int)h) << 16;
    return v.f;
}

// ---------------------------------------------------------------------------
__global__ void cast_f32_bf16(const float* __restrict__ src,
                              unsigned short* __restrict__ dst, int n4)
{
    const int i = blockIdx.x * blockDim.x + threadIdx.x;
    if (i < n4) {
        const float4 v = *(const float4*)(src + (size_t)i * 4);
        u16x4 o;
        o[0] = f2bf(v.x); o[1] = f2bf(v.y); o[2] = f2bf(v.z); o[3] = f2bf(v.w);
        *(u16x4*)(dst + (size_t)i * 4) = o;
    }
}

// ---------------------------------------------------------------------------
// MFMA GEMM 1, 8-wave (512 thr) blocks: same 128x128 tile, per-wave 64x32
// sub-tile (4 m-frags x 2 n-frags). Fused f32->bf16 transpose staging of x.
// 2x TLP vs 4-wave version to hide staging latency (occupancy was 22%).
// ---------------------------------------------------------------------------
__global__ __launch_bounds__(512)
void gemm_value_mfma(const unsigned short* __restrict__ Wb,
                     const float* __restrict__ x,
                     const float* __restrict__ bv,
                     const unsigned char* __restrict__ mask,
                     unsigned short* __restrict__ valb)
{
    __shared__ unsigned short Wl[128 * PITCH];
    __shared__ unsigned short Al[128 * PITCH];
    const int n  = blockIdx.z;
    const int ob = blockIdx.y * 128;
    const int sb = blockIdx.x * 128;
    const int tid = threadIdx.x;

    // ---- W staging: 128 rows x 32 k, 512 threads x one u16x8
    const int r   = tid >> 2;          // 0..127
    const int seg = (tid & 3) * 8;     // 0,8,16,24
    const unsigned short* wsrc = Wb + ((size_t)(ob + r)) * CCH + seg;
    unsigned short* wdst = &Wl[r * PITCH + seg];

    // ---- Act transposed staging: 32 c x 128 s f32, 4 float2/thread
    const int sp   = tid & 15;          // s-pair
    const int cgrp = (tid >> 4) & 15;   // k-pair id: k = 2*cgrp + cc
    const int half = tid >> 8;          // j = 2*half + jj
    const size_t XLIM = (size_t)NBATCH * CCH * TOT_S - 2;

    const int wave = tid >> 6, lane = tid & 63;
    const int m0 = (wave & 1) * 64, n0 = (wave >> 1) * 32;
    const int row16 = lane & 15, q = lane >> 4;

    u16x8 w0 = *(const u16x8*)(wsrc);
    float2 ax[2][2];
#pragma unroll
    for (int cc = 0; cc < 2; ++cc)
#pragma unroll
        for (int jj = 0; jj < 2; ++jj) {
            const int j = 2 * half + jj;
            size_t off = ((size_t)n * CCH + 2 * cgrp + cc) * TOT_S
                       + sb + 2 * sp + 32 * j;
            off = off > XLIM ? XLIM : off;
            ax[cc][jj] = *(const float2*)(x + off);
        }

    f32x4 acc[4][2] = {};
    for (int k0 = 0; k0 < CCH; k0 += 32) {
        *(u16x8*)wdst = w0;
#pragma unroll
        for (int jj = 0; jj < 2; ++jj)
#pragma unroll
            for (int i = 0; i < 2; ++i) {
                const int s = 2 * sp + 32 * (2 * half + jj) + i;
                const float lo = i ? ax[0][jj].y : ax[0][jj].x;
                const float hi = i ? ax[1][jj].y : ax[1][jj].x;
                const unsigned int pk =
                    (unsigned int)f2bf(lo) | ((unsigned int)f2bf(hi) << 16);
                *(unsigned int*)&Al[(size_t)s * PITCH + 2 * cgrp] = pk;
            }
        __syncthreads();
        if (k0 + 32 < CCH) {
            w0 = *(const u16x8*)(wsrc + k0 + 32);
#pragma unroll
            for (int cc = 0; cc < 2; ++cc)
#pragma unroll
                for (int jj = 0; jj < 2; ++jj) {
                    const int j = 2 * half + jj;
                    size_t off = ((size_t)n * CCH + k0 + 32 + 2 * cgrp + cc) * TOT_S
                               + sb + 2 * sp + 32 * j;
                    off = off > XLIM ? XLIM : off;
                    ax[cc][jj] = *(const float2*)(x + off);
                }
        }
        short8 af[4], bfr[2];
#pragma unroll
        for (int mt = 0; mt < 4; ++mt)
            af[mt] = *(const short8*)&Wl[(m0 + mt * 16 + row16) * PITCH + q * 8];
#pragma unroll
        for (int nt = 0; nt < 2; ++nt)
            bfr[nt] = *(const short8*)&Al[(n0 + nt * 16 + row16) * PITCH + q * 8];
#pragma unroll
        for (int mt = 0; mt < 4; ++mt)
#pragma unroll
            for (int nt = 0; nt < 2; ++nt)
                acc[mt][nt] = __builtin_amdgcn_mfma_f32_16x16x32_bf16(
                    af[mt], bfr[nt], acc[mt][nt], 0, 0, 0);
        __syncthreads();
    }

#pragma unroll
    for (int nt = 0; nt < 2; ++nt) {
        const int s = sb + n0 + nt * 16 + row16;
        if (s >= TOT_S) continue;
        const float msk = mask[(size_t)n * TOT_S + s] ? 0.f : 1.f;
        unsigned short* orow = valb + ((size_t)n * TOT_S + s) * CCH + ob + m0;
#pragma unroll
        for (int mt = 0; mt < 4; ++mt) {
            const f32x4 bvv = *(const f32x4*)(bv + ob + m0 + mt * 16 + q * 4);
            const f32x4 a = acc[mt][nt];
            u16x4 ov;
            ov[0] = f2bf((a[0] + bvv[0]) * msk);
            ov[1] = f2bf((a[1] + bvv[1]) * msk);
            ov[2] = f2bf((a[2] + bvv[2]) * msk);
            ov[3] = f2bf((a[3] + bvv[3]) * msk);
            *(u16x4*)(orow + mt * 16 + q * 4) = ov;
        }
    }
}

// ---------------------------------------------------------------------------
// MFMA GEMM 2 (offsets+logits), fused transpose staging of (x+pos)*~mask.
// ---------------------------------------------------------------------------
__global__ __launch_bounds__(256)
void gemm_offw_mfma(const unsigned short* __restrict__ Wlb,
                    const unsigned short* __restrict__ Wwb,
                    const float* __restrict__ bloc, const float* __restrict__ bw,
                    const float* __restrict__ x, const float* __restrict__ pos,
                    const unsigned char* __restrict__ mask,
                    float* __restrict__ offw)
{
    __shared__ unsigned short Wl[128 * PITCH];
    __shared__ unsigned short Al[128 * PITCH];
    const int n  = blockIdx.z;
    const int sb = blockIdx.x * 128;
    const int tid = threadIdx.x;

    // ---- W staging (unchanged)
    const int r   = tid >> 1;
    const int seg = (tid & 1) * 16;
    const bool wzero = (r >= 96);
    const unsigned short* wsrc =
        (r < 64) ? (Wlb + (size_t)r * CCH + seg)
                 : (Wwb + (size_t)((r < 96 ? r : 95) - 64) * CCH + seg);
    unsigned short* wdst = &Wl[r * PITCH + seg];

    // ---- Act transposed-staging mapping
    const int sp   = tid & 15;
    const int cpid = tid >> 4;
    const size_t XLIM = (size_t)NBATCH * CCH * TOT_S - 2;
    float mkm[8];
#pragma unroll
    for (int j = 0; j < 4; ++j)
#pragma unroll
        for (int i = 0; i < 2; ++i) {
            const int s = sb + 2 * sp + 32 * j + i;
            const int sc = s < TOT_S ? s : TOT_S - 1;
            mkm[j * 2 + i] = mask[(size_t)n * TOT_S + sc] ? 0.f : 1.f;
        }

    const int wave = tid >> 6, lane = tid & 63;
    const int m0 = (wave & 1) * 64, n0 = (wave >> 1) * 64;
    const int row16 = lane & 15, q = lane >> 4;

    u16x8 w0 = {}, w1 = {};
    if (!wzero) { w0 = *(const u16x8*)(wsrc); w1 = *(const u16x8*)(wsrc + 8); }
    float2 ax[2][4], ap[2][4];
#pragma unroll
    for (int cc = 0; cc < 2; ++cc)
#pragma unroll
        for (int j = 0; j < 4; ++j) {
            size_t off = ((size_t)n * CCH + 2 * cpid + cc) * TOT_S
                       + sb + 2 * sp + 32 * j;
            off = off > XLIM ? XLIM : off;
            ax[cc][j] = *(const float2*)(x + off);
            ap[cc][j] = *(const float2*)(pos + off);
        }

    f32x4 acc[4][4] = {};
    for (int k0 = 0; k0 < CCH; k0 += 32) {
        *(u16x8*)wdst = w0; *(u16x8*)(wdst + 8) = w1;
#pragma unroll
        for (int j = 0; j < 4; ++j)
#pragma unroll
            for (int i = 0; i < 2; ++i) {
                const int s = 2 * sp + 32 * j + i;
                const float lo = (i ? ax[0][j].y + ap[0][j].y
                                    : ax[0][j].x + ap[0][j].x) * mkm[j * 2 + i];
                const float hi = (i ? ax[1][j].y + ap[1][j].y
                                    : ax[1][j].x + ap[1][j].x) * mkm[j * 2 + i];
                const unsigned int pk =
                    (unsigned int)f2bf(lo) | ((unsigned int)f2bf(hi) << 16);
                *(unsigned int*)&Al[(size_t)s * PITCH + 2 * cpid] = pk;
            }
        __syncthreads();
        if (k0 + 32 < CCH) {
            if (!wzero) {
                w0 = *(const u16x8*)(wsrc + k0 + 32);
                w1 = *(const u16x8*)(wsrc + k0 + 40);
            }
#pragma unroll
            for (int cc = 0; cc < 2; ++cc)
#pragma unroll
                for (int j = 0; j < 4; ++j) {
                    size_t off = ((size_t)n * CCH + k0 + 32 + 2 * cpid + cc) * TOT_S
                               + sb + 2 * sp + 32 * j;
                    off = off > XLIM ? XLIM : off;
                    ax[cc][j] = *(const float2*)(x + off);
                    ap[cc][j] = *(const float2*)(pos + off);
                }
        }
        short8 af[4], bfr[4];
#pragma unroll
        for (int mt = 0; mt < 4; ++mt)
            af[mt] = *(const short8*)&Wl[(m0 + mt * 16 + row16) * PITCH + q * 8];
#pragma unroll
        for (int nt = 0; nt < 4; ++nt)
            bfr[nt] = *(const short8*)&Al[(n0 + nt * 16 + row16) * PITCH + q * 8];
#pragma unroll
        for (int mt = 0; mt < 4; ++mt)
#pragma unroll
            for (int nt = 0; nt < 4; ++nt)
                acc[mt][nt] = __builtin_amdgcn_mfma_f32_16x16x32_bf16(
                    af[mt], bfr[nt], acc[mt][nt], 0, 0, 0);
        __syncthreads();
    }

#pragma unroll
    for (int nt = 0; nt < 4; ++nt) {
        const int s = sb + n0 + nt * 16 + row16;
        if (s >= TOT_S) continue;
        float* orow = offw + ((size_t)n * TOT_S + s) * 96;
#pragma unroll
        for (int mt = 0; mt < 4; ++mt) {
            const int o = m0 + mt * 16 + q * 4;
            if (o < 96) {
                const float* bsrc = (o < 64) ? (bloc + o) : (bw + o - 64);
                const f32x4 bb = *(const f32x4*)bsrc;
                f32x4 v = acc[mt][nt];
                v[0] += bb[0]; v[1] += bb[1]; v[2] += bb[2]; v[3] += bb[3];
                *(f32x4*)(orow + o) = v;
            }
        }
    }
}

// ---------------------------------------------------------------------------
// Sampling v2: ONE WAVE PER (n,s). lane -> head m = lane>>3, channels
// c = m*64 + (lane&7)*8 .. +8  (== lane*8: output row is one contiguous 1KiB
// store). 16B/lane gathers; branchless clamp + masked corner weights.
// ---------------------------------------------------------------------------
__global__ __launch_bounds__(256)
void sample_attn(const unsigned short* __restrict__ value,  // (N,S,512) bf16
                 const float* __restrict__ offw,            // (N,S,96)
                 const float* __restrict__ vsizes,
                 const float* __restrict__ vscales,
                 unsigned short* __restrict__ samp)         // (N,S,512) bf16
{
    const int lane = threadIdx.x;
    const int item = blockIdx.x * blockDim.y + threadIdx.y;
    const int total = NBATCH * TOT_S;
    if (item >= total) return;
    const int s = item % TOT_S;
    const int n = item / TOT_S;
    const int m = lane >> 3;

    // query level + pixel-center coords (wave-uniform)
    int lvl; float prex, prey;
    if (s < 10000)      { lvl = 0; const int l = s;         const int qq = l / 100; prey = qq + 0.5f; prex = (l - qq * 100) + 0.5f; }
    else if (s < 12500) { lvl = 1; const int l = s - 10000; const int qq = l / 50;  prey = qq + 0.5f; prex = (l - qq * 50)  + 0.5f; }
    else if (s < 13125) { lvl = 2; const int l = s - 12500; const int qq = l / 25;  prey = qq + 0.5f; prex = (l - qq * 25)  + 0.5f; }
    else                { lvl = 3; const int l = s - 13125; const int qq = l / 13;  prey = qq + 0.5f; prex = (l - qq * 13)  + 0.5f; }

    const float* ow = offw + ((size_t)n * TOT_S + s) * 96;

    // per-head softmax over 4 logits (replicated across the 8 lanes of a head)
    const float w0 = ow[64 + m * 4 + 0], w1 = ow[64 + m * 4 + 1];
    const float w2 = ow[64 + m * 4 + 2], w3 = ow[64 + m * 4 + 3];
    const float mx = fmaxf(fmaxf(w0, w1), fmaxf(w2, w3));
    const float e0 = expf(w0 - mx), e1 = expf(w1 - mx), e2 = expf(w2 - mx), e3 = expf(w3 - mx);
    const float inv = 1.f / (e0 + e1 + e2 + e3);
    const float wgt[4] = { e0 * inv, e1 * inv, e2 * inv, e3 * inv };

    const int HS[4]  = { 100, 50, 25, 13 };
    const int WS[4]  = { 100, 50, 25, 13 };
    const int CUR[4] = { 0, 10000, 12500, 13125 };

    const float invsx = 1.f / vsizes[((n * 4) + lvl) * 2 + 0];
    const float invsy = 1.f / vsizes[((n * 4) + lvl) * 2 + 1];
    // channel base: c = lane*8
    const unsigned short* vbase = value + (size_t)n * TOT_S * CCH + lane * 8;

    float acc[8] = {};
#pragma unroll
    for (int f = 0; f < 4; ++f) {
        const float offx = ow[(m * 4 + f) * 2 + 0];
        const float offy = ow[(m * 4 + f) * 2 + 1];
        const float scx = 2.f * vscales[((n * 4) + f) * 2 + 0] * invsx;
        const float scy = 2.f * vscales[((n * 4) + f) * 2 + 1] * invsy;
        const int Wf = WS[f], Hf = HS[f], cf = CUR[f];
        const float xi = (offx + prex) * scx * (Wf * 0.5f) - 0.5f;
        const float yi = (offy + prey) * scy * (Hf * 0.5f) - 0.5f;
        const float x0f = floorf(xi), y0f = floorf(yi);
        const float wx1 = xi - x0f, wy1 = yi - y0f;
        const float wx0 = 1.f - wx1, wy0 = 1.f - wy1;
        const int x0 = (int)x0f, y0 = (int)y0f;
        const bool xin0 = (x0 >= 0) && (x0 < Wf);
        const bool xin1 = (x0 + 1 >= 0) && (x0 + 1 < Wf);
        const bool yin0 = (y0 >= 0) && (y0 < Hf);
        const bool yin1 = (y0 + 1 >= 0) && (y0 + 1 < Hf);
        // masked corner weights (fold level weight in), clamped indices
        const float cw00 = (xin0 && yin0) ? wgt[f] * wx0 * wy0 : 0.f;
        const float cw10 = (xin1 && yin0) ? wgt[f] * wx1 * wy0 : 0.f;
        const float cw01 = (xin0 && yin1) ? wgt[f] * wx0 * wy1 : 0.f;
        const float cw11 = (xin1 && yin1) ? wgt[f] * wx1 * wy1 : 0.f;
        const int x0c = min(max(x0, 0), Wf - 1);
        const int x1c = min(max(x0 + 1, 0), Wf - 1);
        const int y0c = min(max(y0, 0), Hf - 1);
        const int y1c = min(max(y0 + 1, 0), Hf - 1);
        const unsigned short* row0 = vbase + (size_t)(cf + y0c * Wf) * CCH;
        const unsigned short* row1 = vbase + (size_t)(cf + y1c * Wf) * CCH;
        const u16x8 v00 = *(const u16x8*)(row0 + (size_t)x0c * CCH);
        const u16x8 v10 = *(const u16x8*)(row0 + (size_t)x1c * CCH);
        const u16x8 v01 = *(const u16x8*)(row1 + (size_t)x0c * CCH);
        const u16x8 v11 = *(const u16x8*)(row1 + (size_t)x1c * CCH);
#pragma unroll
        for (int j = 0; j < 8; ++j) {
            acc[j] += cw00 * bf2f(v00[j]) + cw10 * bf2f(v10[j])
                    + cw01 * bf2f(v01[j]) + cw11 * bf2f(v11[j]);
        }
    }

    u16x8 ov;
#pragma unroll
    for (int j = 0; j < 8; ++j) ov[j] = f2bf(acc[j]);
    *(u16x8*)(samp + ((size_t)n * TOT_S + s) * CCH + lane * 8) = ov;
}

// ---------------------------------------------------------------------------
// MFMA GEMM 3, 8-wave blocks (same restructure as GEMM 1):
// out[n][o][s] = (sum_c Wo[o][c]*samp[s][c] + bo[o]) * scale[o]
// ---------------------------------------------------------------------------
__global__ __launch_bounds__(512)
void gemm_out_mfma(const unsigned short* __restrict__ Wob,
                   const unsigned short* __restrict__ Sampb,
                   const float* __restrict__ bo, const float* __restrict__ scale,
                   float* __restrict__ out)
{
    __shared__ unsigned short Sl[128 * PITCH];
    __shared__ unsigned short Wl[128 * PITCH];
    const int n  = blockIdx.z;
    const int ob = blockIdx.y * 128;
    const int sb = blockIdx.x * 128;
    const int tid = threadIdx.x;
    const int r   = tid >> 2;          // 0..127
    const int seg = (tid & 3) * 8;     // 0,8,16,24
    const int sr = min(sb + r, TOT_S - 1);
    const unsigned short* ssrc = Sampb + ((size_t)n * TOT_S + sr) * CCH + seg;
    const unsigned short* wsrc = Wob + ((size_t)(ob + r)) * CCH + seg;
    unsigned short* sdst = &Sl[r * PITCH + seg];
    unsigned short* wdst = &Wl[r * PITCH + seg];

    const int wave = tid >> 6, lane = tid & 63;
    const int m0 = (wave & 1) * 64, n0 = (wave >> 1) * 32;
    const int row16 = lane & 15, q = lane >> 4;

    u16x8 s0v = *(const u16x8*)(ssrc);
    u16x8 w0v = *(const u16x8*)(wsrc);

    f32x4 acc[4][2] = {};
    for (int k0 = 0; k0 < CCH; k0 += 32) {
        *(u16x8*)sdst = s0v;
        *(u16x8*)wdst = w0v;
        __syncthreads();
        if (k0 + 32 < CCH) {
            s0v = *(const u16x8*)(ssrc + k0 + 32);
            w0v = *(const u16x8*)(wsrc + k0 + 32);
        }
        short8 af[4], bfr[2];
#pragma unroll
        for (int mt = 0; mt < 4; ++mt)
            af[mt] = *(const short8*)&Sl[(m0 + mt * 16 + row16) * PITCH + q * 8];
#pragma unroll
        for (int nt = 0; nt < 2; ++nt)
            bfr[nt] = *(const short8*)&Wl[(n0 + nt * 16 + row16) * PITCH + q * 8];
#pragma unroll
        for (int mt = 0; mt < 4; ++mt)
#pragma unroll
            for (int nt = 0; nt < 2; ++nt)
                acc[mt][nt] = __builtin_amdgcn_mfma_f32_16x16x32_bf16(
                    af[mt], bfr[nt], acc[mt][nt], 0, 0, 0);
        __syncthreads();
    }

#pragma unroll
    for (int nt = 0; nt < 2; ++nt) {
        const int o = ob + n0 + nt * 16 + row16;
        const float bo_ = bo[o];
        const float sc_ = scale[o];
        float* orow = out + ((size_t)n * CCH + o) * (size_t)TOT_S;
#pragma unroll
        for (int mt = 0; mt < 4; ++mt) {
            const int s0 = sb + m0 + mt * 16 + q * 4;
            const f32x4 a = acc[mt][nt];
            if (s0 + 3 < TOT_S) {
                float2 v0 = make_float2((a[0] + bo_) * sc_, (a[1] + bo_) * sc_);
                float2 v1 = make_float2((a[2] + bo_) * sc_, (a[3] + bo_) * sc_);
                *(float2*)(orow + s0) = v0;
                *(float2*)(orow + s0 + 2) = v1;
            } else {
                for (int i = 0; i < 4; ++i)
                    if (s0 + i < TOT_S) orow[s0 + i] = (a[i] + bo_) * sc_;
            }
        }
    }
}

// ---------------------------------------------------------------------------
extern "C" void kernel_launch(void* const* d_in, const int* in_sizes, int n_in,
                              void* d_out, int out_size, void* d_ws, size_t ws_size,
                              hipStream_t stream)
{
    const float* x     = (const float*)d_in[0];
    const float* pos   = (const float*)d_in[1];
    const unsigned char* mask = (const unsigned char*)d_in[2];
    const float* vsz   = (const float*)d_in[3];
    const float* vsc   = (const float*)d_in[4];
    const float* Wv    = (const float*)d_in[5];
    const float* bv    = (const float*)d_in[6];
    const float* Wloc  = (const float*)d_in[7];
    const float* bloc  = (const float*)d_in[8];
    const float* Ww    = (const float*)d_in[9];
    const float* bw    = (const float*)d_in[10];
    const float* Wo    = (const float*)d_in[11];
    const float* bo    = (const float*)d_in[12];
    const float* scale = (const float*)d_in[13];
    float* out = (float*)d_out;

    const size_t SC = (size_t)TOT_S * CCH;
    unsigned short* valb  = (unsigned short*)d_ws;
    unsigned short* sampb = valb  + 2 * SC;
    float* offw = (float*)(sampb + 2 * SC);
    unsigned short* wvb = (unsigned short*)(offw + 2 * (size_t)TOT_S * 96);
    unsigned short* wob = wvb + 512 * 512;
    unsigned short* wlb = wob + 512 * 512;
    unsigned short* wwb = wlb + 64 * 512;

    cast_f32_bf16<<<256, 256, 0, stream>>>(Wv,   wvb, 512 * 512 / 4);
    cast_f32_bf16<<<256, 256, 0, stream>>>(Wo,   wob, 512 * 512 / 4);
    cast_f32_bf16<<<32,  256, 0, stream>>>(Wloc, wlb, 64 * 512 / 4);
    cast_f32_bf16<<<16,  256, 0, stream>>>(Ww,   wwb, 32 * 512 / 4);

    const int sTiles = (TOT_S + 127) / 128;  // 104

    gemm_value_mfma<<<dim3(sTiles, CCH / 128, NBATCH), 512, 0, stream>>>(
        wvb, x, bv, mask, valb);
    gemm_offw_mfma<<<dim3(sTiles, 1, NBATCH), 256, 0, stream>>>(
        wlb, wwb, bloc, bw, x, pos, mask, offw);

    const int items = NBATCH * TOT_S;   // one wave per (n,s)
    sample_attn<<<(items + 3) / 4, dim3(64, 4), 0, stream>>>(valb, offw, vsz, vsc, sampb);

    gemm_out_mfma<<<dim3(sTiles, CCH / 128, NBATCH), 512, 0, stream>>>(
        wob, sampb, bo, scale, out);
}

// Round 8
// 283.772 us; speedup vs baseline: 1.0860x; 1.0112x over previous
//
#include <hip/hip_runtime.h>
#include <math.h>

#define TOT_S   13294
#define NBATCH  2
#define CCH     512
#define MHEAD   8
#define PITCH   40   // LDS row pitch in bf16 elems (32 + 8 pad -> 80B)

typedef short     short8  __attribute__((ext_vector_type(8)));
typedef float     f32x4   __attribute__((ext_vector_type(4)));
typedef unsigned short u16x8 __attribute__((ext_vector_type(8)));
typedef unsigned short u16x4 __attribute__((ext_vector_type(4)));

__device__ __forceinline__ unsigned short f2bf(float f) {
    union { float f; unsigned int u; } v; v.f = f;
    unsigned int r = v.u + 0x7fffu + ((v.u >> 16) & 1u);   // RNE
    return (unsigned short)(r >> 16);
}
__device__ __forceinline__ float bf2f(unsigned short h) {
    union { unsigned int u; float f; } v; v.u = ((unsigned int)h) << 16;
    return v.f;
}

// ---------------------------------------------------------------------------
__global__ void cast_f32_bf16(const float* __restrict__ src,
                              unsigned short* __restrict__ dst, int n4)
{
    const int i = blockIdx.x * blockDim.x + threadIdx.x;
    if (i < n4) {
        const float4 v = *(const float4*)(src + (size_t)i * 4);
        u16x4 o;
        o[0] = f2bf(v.x); o[1] = f2bf(v.y); o[2] = f2bf(v.z); o[3] = f2bf(v.w);
        *(u16x4*)(dst + (size_t)i * 4) = o;
    }
}

// ---------------------------------------------------------------------------
// MFMA GEMM 1 v3: o-tile 256 x s-tile 128, 8 waves (4 o-waves x 2 s-waves),
// per-wave 64x64 -> 16 MFMA/phase (was 8). Fused f32->bf16 transpose staging
// of x; Act staging redundancy halved (2 o-tiles instead of 4).
// ---------------------------------------------------------------------------
__global__ __launch_bounds__(512)
void gemm_value_mfma(const unsigned short* __restrict__ Wb,
                     const float* __restrict__ x,
                     const float* __restrict__ bv,
                     const unsigned char* __restrict__ mask,
                     unsigned short* __restrict__ valb)
{
    __shared__ unsigned short Wl[256 * PITCH];   // 20.0 KB
    __shared__ unsigned short Al[128 * PITCH];   // 10.0 KB
    const int n  = blockIdx.z;
    const int ob = blockIdx.y * 256;
    const int sb = blockIdx.x * 128;
    const int tid = threadIdx.x;

    // ---- W staging: 256 rows x 32 k; thread -> row tid>>1, 16-elem half
    const int r2  = tid >> 1;
    const int sg2 = (tid & 1) * 16;
    const unsigned short* wsrc = Wb + ((size_t)(ob + r2)) * CCH + sg2;
    unsigned short* wdst = &Wl[r2 * PITCH + sg2];

    // ---- Act transposed staging: 32 c x 128 s f32, 4 float2/thread
    const int sp   = tid & 15;          // s-pair
    const int cgrp = (tid >> 4) & 15;   // k-pair id: k = 2*cgrp + cc
    const int half = tid >> 8;          // j = 2*half + jj
    const size_t XLIM = (size_t)NBATCH * CCH * TOT_S - 2;

    const int wave = tid >> 6, lane = tid & 63;
    const int m0 = (wave & 3) * 64;     // o-offset within 256
    const int n0 = (wave >> 2) * 64;    // s-offset within 128
    const int row16 = lane & 15, q = lane >> 4;

    u16x8 w0 = *(const u16x8*)(wsrc);
    u16x8 w1 = *(const u16x8*)(wsrc + 8);
    float2 ax[2][2];
#pragma unroll
    for (int cc = 0; cc < 2; ++cc)
#pragma unroll
        for (int jj = 0; jj < 2; ++jj) {
            const int j = 2 * half + jj;
            size_t off = ((size_t)n * CCH + 2 * cgrp + cc) * TOT_S
                       + sb + 2 * sp + 32 * j;
            off = off > XLIM ? XLIM : off;
            ax[cc][jj] = *(const float2*)(x + off);
        }

    f32x4 acc[4][4] = {};
    for (int k0 = 0; k0 < CCH; k0 += 32) {
        *(u16x8*)wdst = w0; *(u16x8*)(wdst + 8) = w1;
#pragma unroll
        for (int jj = 0; jj < 2; ++jj)
#pragma unroll
            for (int i = 0; i < 2; ++i) {
                const int s = 2 * sp + 32 * (2 * half + jj) + i;
                const float lo = i ? ax[0][jj].y : ax[0][jj].x;
                const float hi = i ? ax[1][jj].y : ax[1][jj].x;
                const unsigned int pk =
                    (unsigned int)f2bf(lo) | ((unsigned int)f2bf(hi) << 16);
                *(unsigned int*)&Al[(size_t)s * PITCH + 2 * cgrp] = pk;
            }
        __syncthreads();
        if (k0 + 32 < CCH) {
            w0 = *(const u16x8*)(wsrc + k0 + 32);
            w1 = *(const u16x8*)(wsrc + k0 + 40);
#pragma unroll
            for (int cc = 0; cc < 2; ++cc)
#pragma unroll
                for (int jj = 0; jj < 2; ++jj) {
                    const int j = 2 * half + jj;
                    size_t off = ((size_t)n * CCH + k0 + 32 + 2 * cgrp + cc) * TOT_S
                               + sb + 2 * sp + 32 * j;
                    off = off > XLIM ? XLIM : off;
                    ax[cc][jj] = *(const float2*)(x + off);
                }
        }
        short8 af[4], bfr[4];
#pragma unroll
        for (int mt = 0; mt < 4; ++mt)
            af[mt] = *(const short8*)&Wl[(m0 + mt * 16 + row16) * PITCH + q * 8];
#pragma unroll
        for (int nt = 0; nt < 4; ++nt)
            bfr[nt] = *(const short8*)&Al[(n0 + nt * 16 + row16) * PITCH + q * 8];
#pragma unroll
        for (int mt = 0; mt < 4; ++mt)
#pragma unroll
            for (int nt = 0; nt < 4; ++nt)
                acc[mt][nt] = __builtin_amdgcn_mfma_f32_16x16x32_bf16(
                    af[mt], bfr[nt], acc[mt][nt], 0, 0, 0);
        __syncthreads();
    }

#pragma unroll
    for (int nt = 0; nt < 4; ++nt) {
        const int s = sb + n0 + nt * 16 + row16;
        if (s >= TOT_S) continue;
        const float msk = mask[(size_t)n * TOT_S + s] ? 0.f : 1.f;
        unsigned short* orow = valb + ((size_t)n * TOT_S + s) * CCH + ob + m0;
#pragma unroll
        for (int mt = 0; mt < 4; ++mt) {
            const f32x4 bvv = *(const f32x4*)(bv + ob + m0 + mt * 16 + q * 4);
            const f32x4 a = acc[mt][nt];
            u16x4 ov;
            ov[0] = f2bf((a[0] + bvv[0]) * msk);
            ov[1] = f2bf((a[1] + bvv[1]) * msk);
            ov[2] = f2bf((a[2] + bvv[2]) * msk);
            ov[3] = f2bf((a[3] + bvv[3]) * msk);
            *(u16x4*)(orow + mt * 16 + q * 4) = ov;
        }
    }
}

// ---------------------------------------------------------------------------
// MFMA GEMM 2 (offsets+logits), fused transpose staging of (x+pos)*~mask.
// ---------------------------------------------------------------------------
__global__ __launch_bounds__(256)
void gemm_offw_mfma(const unsigned short* __restrict__ Wlb,
                    const unsigned short* __restrict__ Wwb,
                    const float* __restrict__ bloc, const float* __restrict__ bw,
                    const float* __restrict__ x, const float* __restrict__ pos,
                    const unsigned char* __restrict__ mask,
                    float* __restrict__ offw)
{
    __shared__ unsigned short Wl[128 * PITCH];
    __shared__ unsigned short Al[128 * PITCH];
    const int n  = blockIdx.z;
    const int sb = blockIdx.x * 128;
    const int tid = threadIdx.x;

    // ---- W staging (unchanged)
    const int r   = tid >> 1;
    const int seg = (tid & 1) * 16;
    const bool wzero = (r >= 96);
    const unsigned short* wsrc =
        (r < 64) ? (Wlb + (size_t)r * CCH + seg)
                 : (Wwb + (size_t)((r < 96 ? r : 95) - 64) * CCH + seg);
    unsigned short* wdst = &Wl[r * PITCH + seg];

    // ---- Act transposed-staging mapping
    const int sp   = tid & 15;
    const int cpid = tid >> 4;
    const size_t XLIM = (size_t)NBATCH * CCH * TOT_S - 2;
    float mkm[8];
#pragma unroll
    for (int j = 0; j < 4; ++j)
#pragma unroll
        for (int i = 0; i < 2; ++i) {
            const int s = sb + 2 * sp + 32 * j + i;
            const int sc = s < TOT_S ? s : TOT_S - 1;
            mkm[j * 2 + i] = mask[(size_t)n * TOT_S + sc] ? 0.f : 1.f;
        }

    const int wave = tid >> 6, lane = tid & 63;
    const int m0 = (wave & 1) * 64, n0 = (wave >> 1) * 64;
    const int row16 = lane & 15, q = lane >> 4;

    u16x8 w0 = {}, w1 = {};
    if (!wzero) { w0 = *(const u16x8*)(wsrc); w1 = *(const u16x8*)(wsrc + 8); }
    float2 ax[2][4], ap[2][4];
#pragma unroll
    for (int cc = 0; cc < 2; ++cc)
#pragma unroll
        for (int j = 0; j < 4; ++j) {
            size_t off = ((size_t)n * CCH + 2 * cpid + cc) * TOT_S
                       + sb + 2 * sp + 32 * j;
            off = off > XLIM ? XLIM : off;
            ax[cc][j] = *(const float2*)(x + off);
            ap[cc][j] = *(const float2*)(pos + off);
        }

    f32x4 acc[4][4] = {};
    for (int k0 = 0; k0 < CCH; k0 += 32) {
        *(u16x8*)wdst = w0; *(u16x8*)(wdst + 8) = w1;
#pragma unroll
        for (int j = 0; j < 4; ++j)
#pragma unroll
            for (int i = 0; i < 2; ++i) {
                const int s = 2 * sp + 32 * j + i;
                const float lo = (i ? ax[0][j].y + ap[0][j].y
                                    : ax[0][j].x + ap[0][j].x) * mkm[j * 2 + i];
                const float hi = (i ? ax[1][j].y + ap[1][j].y
                                    : ax[1][j].x + ap[1][j].x) * mkm[j * 2 + i];
                const unsigned int pk =
                    (unsigned int)f2bf(lo) | ((unsigned int)f2bf(hi) << 16);
                *(unsigned int*)&Al[(size_t)s * PITCH + 2 * cpid] = pk;
            }
        __syncthreads();
        if (k0 + 32 < CCH) {
            if (!wzero) {
                w0 = *(const u16x8*)(wsrc + k0 + 32);
                w1 = *(const u16x8*)(wsrc + k0 + 40);
            }
#pragma unroll
            for (int cc = 0; cc < 2; ++cc)
#pragma unroll
                for (int j = 0; j < 4; ++j) {
                    size_t off = ((size_t)n * CCH + k0 + 32 + 2 * cpid + cc) * TOT_S
                               + sb + 2 * sp + 32 * j;
                    off = off > XLIM ? XLIM : off;
                    ax[cc][j] = *(const float2*)(x + off);
                    ap[cc][j] = *(const float2*)(pos + off);
                }
        }
        short8 af[4], bfr[4];
#pragma unroll
        for (int mt = 0; mt < 4; ++mt)
            af[mt] = *(const short8*)&Wl[(m0 + mt * 16 + row16) * PITCH + q * 8];
#pragma unroll
        for (int nt = 0; nt < 4; ++nt)
            bfr[nt] = *(const short8*)&Al[(n0 + nt * 16 + row16) * PITCH + q * 8];
#pragma unroll
        for (int mt = 0; mt < 4; ++mt)
#pragma unroll
            for (int nt = 0; nt < 4; ++nt)
                acc[mt][nt] = __builtin_amdgcn_mfma_f32_16x16x32_bf16(
                    af[mt], bfr[nt], acc[mt][nt], 0, 0, 0);
        __syncthreads();
    }

#pragma unroll
    for (int nt = 0; nt < 4; ++nt) {
        const int s = sb + n0 + nt * 16 + row16;
        if (s >= TOT_S) continue;
        float* orow = offw + ((size_t)n * TOT_S + s) * 96;
#pragma unroll
        for (int mt = 0; mt < 4; ++mt) {
            const int o = m0 + mt * 16 + q * 4;
            if (o < 96) {
                const float* bsrc = (o < 64) ? (bloc + o) : (bw + o - 64);
                const f32x4 bb = *(const f32x4*)bsrc;
                f32x4 v = acc[mt][nt];
                v[0] += bb[0]; v[1] += bb[1]; v[2] += bb[2]; v[3] += bb[3];
                *(f32x4*)(orow + o) = v;
            }
        }
    }
}

// ---------------------------------------------------------------------------
// Sampling v2: ONE WAVE PER (n,s). lane -> head m = lane>>3, channels
// c = m*64 + (lane&7)*8 .. +8  (== lane*8: output row is one contiguous 1KiB
// store). 16B/lane gathers; branchless clamp + masked corner weights.
// ---------------------------------------------------------------------------
__global__ __launch_bounds__(256)
void sample_attn(const unsigned short* __restrict__ value,  // (N,S,512) bf16
                 const float* __restrict__ offw,            // (N,S,96)
                 const float* __restrict__ vsizes,
                 const float* __restrict__ vscales,
                 unsigned short* __restrict__ samp)         // (N,S,512) bf16
{
    const int lane = threadIdx.x;
    const int item = blockIdx.x * blockDim.y + threadIdx.y;
    const int total = NBATCH * TOT_S;
    if (item >= total) return;
    const int s = item % TOT_S;
    const int n = item / TOT_S;
    const int m = lane >> 3;

    // query level + pixel-center coords (wave-uniform)
    int lvl; float prex, prey;
    if (s < 10000)      { lvl = 0; const int l = s;         const int qq = l / 100; prey = qq + 0.5f; prex = (l - qq * 100) + 0.5f; }
    else if (s < 12500) { lvl = 1; const int l = s - 10000; const int qq = l / 50;  prey = qq + 0.5f; prex = (l - qq * 50)  + 0.5f; }
    else if (s < 13125) { lvl = 2; const int l = s - 12500; const int qq = l / 25;  prey = qq + 0.5f; prex = (l - qq * 25)  + 0.5f; }
    else                { lvl = 3; const int l = s - 13125; const int qq = l / 13;  prey = qq + 0.5f; prex = (l - qq * 13)  + 0.5f; }

    const float* ow = offw + ((size_t)n * TOT_S + s) * 96;

    // per-head softmax over 4 logits (replicated across the 8 lanes of a head)
    const float w0 = ow[64 + m * 4 + 0], w1 = ow[64 + m * 4 + 1];
    const float w2 = ow[64 + m * 4 + 2], w3 = ow[64 + m * 4 + 3];
    const float mx = fmaxf(fmaxf(w0, w1), fmaxf(w2, w3));
    const float e0 = expf(w0 - mx), e1 = expf(w1 - mx), e2 = expf(w2 - mx), e3 = expf(w3 - mx);
    const float inv = 1.f / (e0 + e1 + e2 + e3);
    const float wgt[4] = { e0 * inv, e1 * inv, e2 * inv, e3 * inv };

    const int HS[4]  = { 100, 50, 25, 13 };
    const int WS[4]  = { 100, 50, 25, 13 };
    const int CUR[4] = { 0, 10000, 12500, 13125 };

    const float invsx = 1.f / vsizes[((n * 4) + lvl) * 2 + 0];
    const float invsy = 1.f / vsizes[((n * 4) + lvl) * 2 + 1];
    // channel base: c = lane*8
    const unsigned short* vbase = value + (size_t)n * TOT_S * CCH + lane * 8;

    float acc[8] = {};
#pragma unroll
    for (int f = 0; f < 4; ++f) {
        const float offx = ow[(m * 4 + f) * 2 + 0];
        const float offy = ow[(m * 4 + f) * 2 + 1];
        const float scx = 2.f * vscales[((n * 4) + f) * 2 + 0] * invsx;
        const float scy = 2.f * vscales[((n * 4) + f) * 2 + 1] * invsy;
        const int Wf = WS[f], Hf = HS[f], cf = CUR[f];
        const float xi = (offx + prex) * scx * (Wf * 0.5f) - 0.5f;
        const float yi = (offy + prey) * scy * (Hf * 0.5f) - 0.5f;
        const float x0f = floorf(xi), y0f = floorf(yi);
        const float wx1 = xi - x0f, wy1 = yi - y0f;
        const float wx0 = 1.f - wx1, wy0 = 1.f - wy1;
        const int x0 = (int)x0f, y0 = (int)y0f;
        const bool xin0 = (x0 >= 0) && (x0 < Wf);
        const bool xin1 = (x0 + 1 >= 0) && (x0 + 1 < Wf);
        const bool yin0 = (y0 >= 0) && (y0 < Hf);
        const bool yin1 = (y0 + 1 >= 0) && (y0 + 1 < Hf);
        // masked corner weights (fold level weight in), clamped indices
        const float cw00 = (xin0 && yin0) ? wgt[f] * wx0 * wy0 : 0.f;
        const float cw10 = (xin1 && yin0) ? wgt[f] * wx1 * wy0 : 0.f;
        const float cw01 = (xin0 && yin1) ? wgt[f] * wx0 * wy1 : 0.f;
        const float cw11 = (xin1 && yin1) ? wgt[f] * wx1 * wy1 : 0.f;
        const int x0c = min(max(x0, 0), Wf - 1);
        const int x1c = min(max(x0 + 1, 0), Wf - 1);
        const int y0c = min(max(y0, 0), Hf - 1);
        const int y1c = min(max(y0 + 1, 0), Hf - 1);
        const unsigned short* row0 = vbase + (size_t)(cf + y0c * Wf) * CCH;
        const unsigned short* row1 = vbase + (size_t)(cf + y1c * Wf) * CCH;
        const u16x8 v00 = *(const u16x8*)(row0 + (size_t)x0c * CCH);
        const u16x8 v10 = *(const u16x8*)(row0 + (size_t)x1c * CCH);
        const u16x8 v01 = *(const u16x8*)(row1 + (size_t)x0c * CCH);
        const u16x8 v11 = *(const u16x8*)(row1 + (size_t)x1c * CCH);
#pragma unroll
        for (int j = 0; j < 8; ++j) {
            acc[j] += cw00 * bf2f(v00[j]) + cw10 * bf2f(v10[j])
                    + cw01 * bf2f(v01[j]) + cw11 * bf2f(v11[j]);
        }
    }

    u16x8 ov;
#pragma unroll
    for (int j = 0; j < 8; ++j) ov[j] = f2bf(acc[j]);
    *(u16x8*)(samp + ((size_t)n * TOT_S + s) * CCH + lane * 8) = ov;
}

// ---------------------------------------------------------------------------
// MFMA GEMM 3 v3: s-tile 128 x o-tile 256, 8 waves (2 s-waves x 4 o-waves),
// per-wave 64x64 -> 16 MFMA/phase. samp staging redundancy halved.
// out[n][o][s] = (sum_c Wo[o][c]*samp[s][c] + bo[o]) * scale[o]
// ---------------------------------------------------------------------------
__global__ __launch_bounds__(512)
void gemm_out_mfma(const unsigned short* __restrict__ Wob,
                   const unsigned short* __restrict__ Sampb,
                   const float* __restrict__ bo, const float* __restrict__ scale,
                   float* __restrict__ out)
{
    __shared__ unsigned short Sl[128 * PITCH];   // 10.0 KB
    __shared__ unsigned short Wl[256 * PITCH];   // 20.0 KB
    const int n  = blockIdx.z;
    const int ob = blockIdx.y * 256;
    const int sb = blockIdx.x * 128;
    const int tid = threadIdx.x;

    // samp staging: 128 rows x 32 k, thread -> row tid>>2, 8-elem quarter
    const int r   = tid >> 2;
    const int seg = (tid & 3) * 8;
    const int sr = min(sb + r, TOT_S - 1);
    const unsigned short* ssrc = Sampb + ((size_t)n * TOT_S + sr) * CCH + seg;
    unsigned short* sdst = &Sl[r * PITCH + seg];

    // W staging: 256 rows x 32 k, thread -> row tid>>1, 16-elem half
    const int r2  = tid >> 1;
    const int sg2 = (tid & 1) * 16;
    const unsigned short* wsrc = Wob + ((size_t)(ob + r2)) * CCH + sg2;
    unsigned short* wdst = &Wl[r2 * PITCH + sg2];

    const int wave = tid >> 6, lane = tid & 63;
    const int m0 = (wave & 1) * 64;     // s-offset within 128
    const int n0 = (wave >> 1) * 64;    // o-offset within 256
    const int row16 = lane & 15, q = lane >> 4;

    u16x8 s0v = *(const u16x8*)(ssrc);
    u16x8 w0v = *(const u16x8*)(wsrc);
    u16x8 w1v = *(const u16x8*)(wsrc + 8);

    f32x4 acc[4][4] = {};
    for (int k0 = 0; k0 < CCH; k0 += 32) {
        *(u16x8*)sdst = s0v;
        *(u16x8*)wdst = w0v; *(u16x8*)(wdst + 8) = w1v;
        __syncthreads();
        if (k0 + 32 < CCH) {
            s0v = *(const u16x8*)(ssrc + k0 + 32);
            w0v = *(const u16x8*)(wsrc + k0 + 32);
            w1v = *(const u16x8*)(wsrc + k0 + 40);
        }
        short8 af[4], bfr[4];
#pragma unroll
        for (int mt = 0; mt < 4; ++mt)
            af[mt] = *(const short8*)&Sl[(m0 + mt * 16 + row16) * PITCH + q * 8];
#pragma unroll
        for (int nt = 0; nt < 4; ++nt)
            bfr[nt] = *(const short8*)&Wl[(n0 + nt * 16 + row16) * PITCH + q * 8];
#pragma unroll
        for (int mt = 0; mt < 4; ++mt)
#pragma unroll
            for (int nt = 0; nt < 4; ++nt)
                acc[mt][nt] = __builtin_amdgcn_mfma_f32_16x16x32_bf16(
                    af[mt], bfr[nt], acc[mt][nt], 0, 0, 0);
        __syncthreads();
    }

#pragma unroll
    for (int nt = 0; nt < 4; ++nt) {
        const int o = ob + n0 + nt * 16 + row16;
        const float bo_ = bo[o];
        const float sc_ = scale[o];
        float* orow = out + ((size_t)n * CCH + o) * (size_t)TOT_S;
#pragma unroll
        for (int mt = 0; mt < 4; ++mt) {
            const int s0 = sb + m0 + mt * 16 + q * 4;
            const f32x4 a = acc[mt][nt];
            if (s0 + 3 < TOT_S) {
                float2 v0 = make_float2((a[0] + bo_) * sc_, (a[1] + bo_) * sc_);
                float2 v1 = make_float2((a[2] + bo_) * sc_, (a[3] + bo_) * sc_);
                *(float2*)(orow + s0) = v0;
                *(float2*)(orow + s0 + 2) = v1;
            } else {
                for (int i = 0; i < 4; ++i)
                    if (s0 + i < TOT_S) orow[s0 + i] = (a[i] + bo_) * sc_;
            }
        }
    }
}

// ---------------------------------------------------------------------------
extern "C" void kernel_launch(void* const* d_in, const int* in_sizes, int n_in,
                              void* d_out, int out_size, void* d_ws, size_t ws_size,
                              hipStream_t stream)
{
    const float* x     = (const float*)d_in[0];
    const float* pos   = (const float*)d_in[1];
    const unsigned char* mask = (const unsigned char*)d_in[2];
    const float* vsz   = (const float*)d_in[3];
    const float* vsc   = (const float*)d_in[4];
    const float* Wv    = (const float*)d_in[5];
    const float* bv    = (const float*)d_in[6];
    const float* Wloc  = (const float*)d_in[7];
    const float* bloc  = (const float*)d_in[8];
    const float* Ww    = (const float*)d_in[9];
    const float* bw    = (const float*)d_in[10];
    const float* Wo    = (const float*)d_in[11];
    const float* bo    = (const float*)d_in[12];
    const float* scale = (const float*)d_in[13];
    float* out = (float*)d_out;

    const size_t SC = (size_t)TOT_S * CCH;
    unsigned short* valb  = (unsigned short*)d_ws;
    unsigned short* sampb = valb  + 2 * SC;
    float* offw = (float*)(sampb + 2 * SC);
    unsigned short* wvb = (unsigned short*)(offw + 2 * (size_t)TOT_S * 96);
    unsigned short* wob = wvb + 512 * 512;
    unsigned short* wlb = wob + 512 * 512;
    unsigned short* wwb = wlb + 64 * 512;

    cast_f32_bf16<<<256, 256, 0, stream>>>(Wv,   wvb, 512 * 512 / 4);
    cast_f32_bf16<<<256, 256, 0, stream>>>(Wo,   wob, 512 * 512 / 4);
    cast_f32_bf16<<<32,  256, 0, stream>>>(Wloc, wlb, 64 * 512 / 4);
    cast_f32_bf16<<<16,  256, 0, stream>>>(Ww,   wwb, 32 * 512 / 4);

    const int sTiles = (TOT_S + 127) / 128;  // 104

    gemm_value_mfma<<<dim3(sTiles, CCH / 256, NBATCH), 512, 0, stream>>>(
        wvb, x, bv, mask, valb);
    gemm_offw_mfma<<<dim3(sTiles, 1, NBATCH), 256, 0, stream>>>(
        wlb, wwb, bloc, bw, x, pos, mask, offw);

    const int items = NBATCH * TOT_S;   // one wave per (n,s)
    sample_attn<<<(items + 3) / 4, dim3(64, 4), 0, stream>>>(valb, offw, vsz, vsc, sampb);

    gemm_out_mfma<<<dim3(sTiles, CCH / 256, NBATCH), 512, 0, stream>>>(
        wob, sampb, bo, scale, out);
}